// Round 18
// baseline (473.406 us; speedup 1.0000x reference)
//
#include <hip/hip_runtime.h>

typedef __bf16 bf16x8 __attribute__((ext_vector_type(8)));
typedef float f32x4 __attribute__((ext_vector_type(4)));
typedef short short8 __attribute__((ext_vector_type(8)));

#define MFMA16(a, b, c) __builtin_amdgcn_mfma_f32_16x16x32_bf16(a, b, c, 0, 0, 0)

__device__ inline unsigned short bf16_rne(float x) {
  unsigned u = __builtin_bit_cast(unsigned, x);
  return (unsigned short)((u + 0x7FFFu + ((u >> 16) & 1u)) >> 16);
}
__device__ inline float bf16_tof(unsigned short s) {
  unsigned u = ((unsigned)s) << 16;
  return __builtin_bit_cast(float, u);
}
__device__ inline void split2(float x, unsigned short* hi, unsigned short* lo) {
  unsigned short h = bf16_rne(x);
  *hi = h;
  *lo = bf16_rne(x - bf16_tof(h));
}
__device__ inline float fast_rcp(float x) { return __builtin_amdgcn_rcpf(x); }

// ---------------- fp32 -> bf16 row conversion (gather source) ----------------

__global__ __launch_bounds__(256) void conv_bf16_kernel(
    const float* __restrict__ x, unsigned short* __restrict__ xb, int total4) {
  int i = blockIdx.x * 256 + threadIdx.x;
  if (i < total4) {
    float4 v = ((const float4*)x)[i];
    ushort4 u;
    u.x = bf16_rne(v.x);
    u.y = bf16_rne(v.y);
    u.z = bf16_rne(v.z);
    u.w = bf16_rne(v.w);
    ((ushort4*)xb)[i] = u;
  }
}

// ---------------- weight frag prep ----------------

__global__ __launch_bounds__(256) void wprep_kernel(
    const float* __restrict__ W, const float* __restrict__ w_ih,
    const float* __restrict__ w_hh, unsigned short* __restrict__ frags) {
  int idx = blockIdx.x * 256 + threadIdx.x;
  if (idx < 1536) {
    int lane = idx & 63;
    int ks = (idx >> 6) % 6;
    int tci = idx / (6 * 64);
    int c = tci * 16 + (lane & 15);
    size_t dbase = ((size_t)(tci * 6 + ks) * 64 + lane) * 8;
#pragma unroll
    for (int j = 0; j < 8; ++j) {
      int k = ks * 32 + ((lane >> 4) << 3) + j;  // 0..191
      int r = k >> 6, d = k & 63;
      float v = W[(r << 12) + (d << 6) + c];
      unsigned short h, l;
      split2(v, &h, &l);
      frags[dbase + j] = h;
      frags[12288 + dbase + j] = l;
    }
  } else if (idx < 1536 + 2 * 1536) {
    int i2 = idx - 1536;
    int set = i2 / 1536;
    int i3 = i2 % 1536;
    int lane = i3 & 63;
    int ks = (i3 >> 6) & 1;
    int tci = (i3 >> 7) % 12;
    int c = tci * 16 + (lane & 15);
    unsigned short* hi = frags + (size_t)(2 + 2 * set) * 12288;
    unsigned short* lo = hi + 12288;
    size_t dbase = ((size_t)(tci * 2 + ks) * 64 + lane) * 8;
    const float* wsrc = set ? w_hh : w_ih;
#pragma unroll
    for (int j = 0; j < 8; ++j) {
      int k = ks * 32 + ((lane >> 4) << 3) + j;
      float v = wsrc[(c << 6) + k];
      unsigned short h, l;
      split2(v, &h, &l);
      hi[dbase + j] = h;
      lo[dbase + j] = l;
    }
  }
}

// ---------------- consolidated CSR build ----------------

__global__ __launch_bounds__(256) void histo_kernel(
    const int* __restrict__ dst, unsigned* __restrict__ bincnt, int E) {
  __shared__ unsigned h[128];
  int tid = threadIdx.x;
  if (tid < 128) h[tid] = 0u;
  __syncthreads();
  int base = blockIdx.x * 2048;
  int lim = base + 2048;
  if (lim > E) lim = E;
  for (int e = base + tid; e < lim; e += 256)
    atomicAdd(&h[((unsigned)dst[e]) >> 10], 1u);
  __syncthreads();
  if (tid < 128) {
    unsigned v = h[tid];
    if (v) atomicAdd(&bincnt[tid], v);
  }
}

__global__ __launch_bounds__(128) void scan128_kernel(
    const unsigned* __restrict__ bincnt, unsigned* __restrict__ binbase,
    unsigned* __restrict__ bincur, unsigned* __restrict__ offs,
    int nbins, int N) {
  __shared__ unsigned sm[128];
  int tid = threadIdx.x;
  unsigned v = (tid < nbins) ? bincnt[tid] : 0u;
  sm[tid] = v;
  __syncthreads();
  for (int ofs = 1; ofs < 128; ofs <<= 1) {
    unsigned add = (tid >= ofs) ? sm[tid - ofs] : 0u;
    __syncthreads();
    sm[tid] += add;
    __syncthreads();
  }
  unsigned excl = sm[tid] - v;
  if (tid < nbins) {
    binbase[tid] = excl;
    bincur[tid] = excl;
  }
  if (tid == 127) {
    binbase[nbins] = sm[127];  // = E
    offs[N] = sm[127];
  }
}

#define SCHUNK 2048
__global__ __launch_bounds__(256) void bin_scatter_kernel(
    const int* __restrict__ src, const int* __restrict__ dst,
    const int* __restrict__ rel, const float* __restrict__ norm,
    unsigned* __restrict__ bincur, uint2* __restrict__ binbuf, int E) {
  __shared__ unsigned cnt[128];
  __shared__ unsigned base[128];
  int tid = threadIdx.x;
  int start = blockIdx.x * SCHUNK;
  if (tid < 128) cnt[tid] = 0u;
  __syncthreads();
  unsigned mybin[8];
  uint2 myrec[8];
#pragma unroll
  for (int i = 0; i < 8; ++i) {
    int e = start + i * 256 + tid;
    if (e < E) {
      int d = dst[e];
      mybin[i] = (unsigned)d >> 10;
      myrec[i].x = (unsigned)src[e] | ((unsigned)rel[e] << 17) |
                   ((unsigned)(d & 1023) << 19);
      myrec[i].y = __builtin_bit_cast(unsigned, norm[e]);
      atomicAdd(&cnt[mybin[i]], 1u);
    } else {
      mybin[i] = 0xFFFFFFFFu;
    }
  }
  __syncthreads();
  if (tid < 128) {
    unsigned c = cnt[tid];
    base[tid] = c ? atomicAdd(&bincur[tid], c) : 0u;
    cnt[tid] = 0u;
  }
  __syncthreads();
#pragma unroll
  for (int i = 0; i < 8; ++i) {
    if (mybin[i] != 0xFFFFFFFFu) {
      unsigned r = atomicAdd(&cnt[mybin[i]], 1u);
      binbuf[base[mybin[i]] + r] = myrec[i];
    }
  }
}

// per-bin (dst,rel) counting sort; computes offs[n] and rcnt[n] in-block
__global__ __launch_bounds__(1024) void bin_sort_kernel(
    const uint2* __restrict__ binbuf, const unsigned* __restrict__ binbase,
    uint2* __restrict__ epack, unsigned* __restrict__ offs,
    unsigned* __restrict__ rcnt, int N) {
  __shared__ unsigned cnt[3 * 1024];
  __shared__ unsigned pos[1024];
  int bin = blockIdx.x;
  int base = bin << 10;
  int tid = threadIdx.x;
  unsigned start = binbase[bin];
  unsigned end = binbase[bin + 1];
  cnt[tid] = 0u;
  cnt[1024 + tid] = 0u;
  cnt[2048 + tid] = 0u;
  __syncthreads();
  for (unsigned j = start + tid; j < end; j += 1024) {
    uint2 rec = binbuf[j];
    atomicAdd(&cnt[((rec.x >> 17) & 3) * 1024 + (rec.x >> 19)], 1u);
  }
  __syncthreads();
  unsigned c0 = cnt[tid], c1 = cnt[1024 + tid], c2 = cnt[2048 + tid];
  unsigned tot = c0 + c1 + c2;
  int n = base + tid;
  if (n < N) rcnt[n] = c0 | (c1 << 16);
  pos[tid] = tot;
  __syncthreads();
  for (int ofs = 1; ofs < 1024; ofs <<= 1) {
    unsigned add = (tid >= ofs) ? pos[tid - ofs] : 0u;
    __syncthreads();
    pos[tid] += add;
    __syncthreads();
  }
  unsigned o = start + pos[tid] - tot;
  if (n < N) offs[n] = o;
  cnt[tid] = o;
  cnt[1024 + tid] = o + c0;
  cnt[2048 + tid] = o + c0 + c1;
  __syncthreads();
  for (unsigned j = start + tid; j < end; j += 1024) {
    uint2 rec = binbuf[j];
    unsigned p = atomicAdd(&cnt[((rec.x >> 17) & 3) * 1024 + (rec.x >> 19)], 1u);
    epack[p] = rec;
  }
}

// ---------------- fused layer: gather + Wcat-GEMM + GRU (R16 structure) ----------------
// Phase 1: one 16-lane group per node, rel-run lambda gather from bf16 rows.
//   (PROVEN: any restructuring of this loop regresses 3x — R13..R17.)
// Phase 2: z @ Wcat (K=192 split-bf16 MFMA) -> swht (LDS).
// Phase 3: GRU MFMAs + register gates; LAYER=1 accumulates BN stats.

template <int LAYER>
__global__ __launch_bounds__(256) void layer_kernel(
    const unsigned short* __restrict__ xbf, const float* __restrict__ xf,
    const unsigned* __restrict__ offs, const unsigned* __restrict__ rcnt,
    const uint2* __restrict__ epack, const unsigned short* __restrict__ wft,
    const unsigned short* __restrict__ wfi, const unsigned short* __restrict__ wfh,
    const float* __restrict__ b_ih, const float* __restrict__ b_hh,
    float* __restrict__ outf, unsigned short* __restrict__ xbfout,
    float* __restrict__ stats, int N) {
  __shared__ float zld[16][197];
  __shared__ float swht[16][69];
  int tid = threadIdx.x;
  int n0 = blockIdx.x << 4;

  // ---- phase 1: gather (rel runs, bf16 rows) ----
  {
    int g = tid >> 4, l16 = tid & 15;
    int n = n0 + g;
    int c4 = l16 << 2;
    float z0[4] = {}, z1[4] = {}, z2[4] = {};
    if (n < N) {
      unsigned a = offs[n], b = offs[n + 1];
      unsigned rc = rcnt[n];
      unsigned b1 = a + (rc & 0xFFFFu), b2 = b1 + (rc >> 16);
      auto run = [&](unsigned s, unsigned e, float* z) {
        unsigned j = s;
        for (; j + 2 <= e; j += 2) {
          uint2 e0 = epack[j], e1 = epack[j + 1];
          ushort4 u0 = *(const ushort4*)(xbf + (((size_t)(e0.x & 0x1FFFFu)) << 6) + c4);
          ushort4 u1 = *(const ushort4*)(xbf + (((size_t)(e1.x & 0x1FFFFu)) << 6) + c4);
          float nv0 = __builtin_bit_cast(float, e0.y);
          float nv1 = __builtin_bit_cast(float, e1.y);
          z[0] = fmaf(nv0, bf16_tof(u0.x), fmaf(nv1, bf16_tof(u1.x), z[0]));
          z[1] = fmaf(nv0, bf16_tof(u0.y), fmaf(nv1, bf16_tof(u1.y), z[1]));
          z[2] = fmaf(nv0, bf16_tof(u0.z), fmaf(nv1, bf16_tof(u1.z), z[2]));
          z[3] = fmaf(nv0, bf16_tof(u0.w), fmaf(nv1, bf16_tof(u1.w), z[3]));
        }
        if (j < e) {
          uint2 e0 = epack[j];
          ushort4 u0 = *(const ushort4*)(xbf + (((size_t)(e0.x & 0x1FFFFu)) << 6) + c4);
          float nv0 = __builtin_bit_cast(float, e0.y);
          z[0] = fmaf(nv0, bf16_tof(u0.x), z[0]);
          z[1] = fmaf(nv0, bf16_tof(u0.y), z[1]);
          z[2] = fmaf(nv0, bf16_tof(u0.z), z[2]);
          z[3] = fmaf(nv0, bf16_tof(u0.w), z[3]);
        }
      };
      run(a, b1, z0);
      run(b1, b2, z1);
      run(b2, b, z2);
    }
#pragma unroll
    for (int i = 0; i < 4; ++i) {
      zld[g][c4 + i] = z0[i];
      zld[g][64 + c4 + i] = z1[i];
      zld[g][128 + c4 + i] = z2[i];
    }
  }
  __syncthreads();

  // ---- phase 2: z @ Wcat (K=192) -> swht ----
  int lane = tid & 63, w = tid >> 6;
  int r15 = lane & 15, kq = lane >> 4;
  {
    const short8* fh = (const short8*)wft;
    const short8* fl = (const short8*)(wft + 12288);
    f32x4 acc = {0.f, 0.f, 0.f, 0.f};
#pragma unroll
    for (int ks = 0; ks < 6; ++ks) {
      const float* zr = &zld[r15][ks * 32 + (kq << 3)];
      short8 th, tl;
#pragma unroll
      for (int jj = 0; jj < 8; ++jj) {
        unsigned short h_, l_;
        split2(zr[jj], &h_, &l_);
        th[jj] = (short)h_;
        tl[jj] = (short)l_;
      }
      bf16x8 ahi = __builtin_bit_cast(bf16x8, th);
      bf16x8 alo = __builtin_bit_cast(bf16x8, tl);
      bf16x8 bhi = __builtin_bit_cast(bf16x8, fh[(w * 6 + ks) * 64 + lane]);
      bf16x8 blo = __builtin_bit_cast(bf16x8, fl[(w * 6 + ks) * 64 + lane]);
      acc = MFMA16(ahi, bhi, acc);
      acc = MFMA16(ahi, blo, acc);
      acc = MFMA16(alo, bhi, acc);
    }
    int c = (w << 4) + r15;
#pragma unroll
    for (int reg = 0; reg < 4; ++reg) swht[(kq << 2) + reg][c] = acc[reg];
  }
  __syncthreads();

  // ---- phase 3: GRU ----
  {
    int c = (w << 4) + r15;
    int row = n0 + r15;
    if (row >= N) row = N - 1;

    bf16x8 axh[2], axl[2], ahh2[2], ahl2[2];
#pragma unroll
    for (int ks = 0; ks < 2; ++ks) {
      const float* sr = &swht[r15][(ks << 5) + (kq << 3)];
      short8 th, tl;
#pragma unroll
      for (int jj = 0; jj < 8; ++jj) {
        unsigned short h_, l_;
        split2(sr[jj], &h_, &l_);
        th[jj] = (short)h_;
        tl[jj] = (short)l_;
      }
      axh[ks] = __builtin_bit_cast(bf16x8, th);
      axl[ks] = __builtin_bit_cast(bf16x8, tl);
    }
    if (LAYER) {
#pragma unroll
      for (int ks = 0; ks < 2; ++ks) {
        const float* hr = xf + (((size_t)row) << 6) + (ks << 5) + (kq << 3);
        float4 h0 = *(const float4*)hr;
        float4 h1v = *(const float4*)(hr + 4);
        float hv[8] = {h0.x, h0.y, h0.z, h0.w, h1v.x, h1v.y, h1v.z, h1v.w};
        short8 th, tl;
#pragma unroll
        for (int jj = 0; jj < 8; ++jj) {
          unsigned short h_, l_;
          split2(hv[jj], &h_, &l_);
          th[jj] = (short)h_;
          tl[jj] = (short)l_;
        }
        ahh2[ks] = __builtin_bit_cast(bf16x8, th);
        ahl2[ks] = __builtin_bit_cast(bf16x8, tl);
      }
    }

    const short8* fih = (const short8*)wfi;
    const short8* fil = (const short8*)(wfi + 12288);
    const short8* fhh = (const short8*)wfh;
    const short8* fhl = (const short8*)(wfh + 12288);
    f32x4 accx[3], acch[3];
#pragma unroll
    for (int g = 0; g < 3; ++g) {
      accx[g] = (f32x4){0.f, 0.f, 0.f, 0.f};
      acch[g] = (f32x4){0.f, 0.f, 0.f, 0.f};
#pragma unroll
      for (int ks = 0; ks < 2; ++ks) {
        int tci = (g << 2) + w;
        bf16x8 bih = __builtin_bit_cast(bf16x8, fih[(tci * 2 + ks) * 64 + lane]);
        bf16x8 bil = __builtin_bit_cast(bf16x8, fil[(tci * 2 + ks) * 64 + lane]);
        accx[g] = MFMA16(axh[ks], bih, accx[g]);
        accx[g] = MFMA16(axh[ks], bil, accx[g]);
        accx[g] = MFMA16(axl[ks], bih, accx[g]);
        if (LAYER) {
          bf16x8 bhh = __builtin_bit_cast(bf16x8, fhh[(tci * 2 + ks) * 64 + lane]);
          bf16x8 bhl = __builtin_bit_cast(bf16x8, fhl[(tci * 2 + ks) * 64 + lane]);
          acch[g] = MFMA16(ahh2[ks], bhh, acch[g]);
          acch[g] = MFMA16(ahh2[ks], bhl, acch[g]);
          acch[g] = MFMA16(ahl2[ks], bhh, acch[g]);
        }
      }
    }

    float bi0 = b_ih[c], bi1 = b_ih[64 + c], bi2 = b_ih[128 + c];
    float bh0 = b_hh[c], bh1 = b_hh[64 + c], bh2 = b_hh[128 + c];
    float bn_s = 0.f, bn_ss = 0.f;
#pragma unroll
    for (int reg = 0; reg < 4; ++reg) {
      int n = n0 + (kq << 2) + reg;
      if (n >= N) break;
      size_t idx = (((size_t)n) << 6) + c;
      float hp = LAYER ? xf[idx] : 0.f;
      float gir = accx[0][reg] + bi0;
      float giz = accx[1][reg] + bi1;
      float gin = accx[2][reg] + bi2;
      float ghr = (LAYER ? acch[0][reg] : 0.f) + bh0;
      float ghz = (LAYER ? acch[1][reg] : 0.f) + bh1;
      float ghn = (LAYER ? acch[2][reg] : 0.f) + bh2;
      float r = fast_rcp(1.f + __expf(-(gir + ghr)));
      float z = fast_rcp(1.f + __expf(-(giz + ghz)));
      float nn = 1.f - 2.f * fast_rcp(1.f + __expf(2.f * (gin + r * ghn)));
      float o = (1.f - z) * nn + z * hp;
      outf[idx] = o;
      if (!LAYER) xbfout[idx] = bf16_rne(o);
      if (LAYER) {
        bn_s += o;
        bn_ss += o * o;
      }
    }
    if (LAYER) {
      bn_s += __shfl_xor(bn_s, 16);
      bn_s += __shfl_xor(bn_s, 32);
      bn_ss += __shfl_xor(bn_ss, 16);
      bn_ss += __shfl_xor(bn_ss, 32);
      if (kq == 0) {
        atomicAdd(&stats[c], bn_s);
        atomicAdd(&stats[64 + c], bn_ss);
      }
    }
  }
}

// ---------------- batchnorm apply ----------------

__global__ __launch_bounds__(256) void bn_apply_kernel(
    float* out, const float* __restrict__ stats,
    const float* __restrict__ gamma, const float* __restrict__ beta,
    int N, int total) {
  int idx = blockIdx.x * 256 + threadIdx.x;
  if (idx >= total) return;
  int c = idx & 63;
  float invN = 1.f / (float)N;
  float mean = stats[c] * invN;
  float var = stats[64 + c] * invN - mean * mean;
  float sc = rsqrtf(var + 1e-5f) * gamma[c];
  float sh = beta[c] - mean * sc;
  out[idx] = out[idx] * sc + sh;
}

// ---------------- launch ----------------

extern "C" void kernel_launch(void* const* d_in, const int* in_sizes, int n_in,
                              void* d_out, int out_size, void* d_ws, size_t ws_size,
                              hipStream_t stream) {
  const float* h     = (const float*)d_in[0];
  const float* norm  = (const float*)d_in[1];
  const float* W     = (const float*)d_in[2];
  const float* w_ih  = (const float*)d_in[3];
  const float* w_hh  = (const float*)d_in[4];
  const float* b_ih  = (const float*)d_in[5];
  const float* b_hh  = (const float*)d_in[6];
  const float* gamma = (const float*)d_in[7];
  const float* beta  = (const float*)d_in[8];
  const int* src     = (const int*)d_in[9];
  const int* dst     = (const int*)d_in[10];
  const int* rel     = (const int*)d_in[11];
  float* out = (float*)d_out;

  const int N = in_sizes[0] / 64;
  const int E = in_sizes[1];
  const int NT = (N + 15) / 16;
  const int NBINS = (N + 1023) / 1024;

  char* wsp = (char*)d_ws;
  float* hf = (float*)wsp;                      wsp += (size_t)N * 64 * 4;  // fp32 h1
  unsigned short* xbf0 = (unsigned short*)wsp;  wsp += (size_t)N * 64 * 2;  // bf16 h0
  unsigned short* xbf1 = (unsigned short*)wsp;  wsp += (size_t)N * 64 * 2;  // bf16 h1
  unsigned short* frags = (unsigned short*)wsp; wsp += 6 * 12288 * 2;
  unsigned* offs = (unsigned*)wsp;    wsp += ((size_t)N + 4) * 4;
  unsigned* rcnt = (unsigned*)wsp;    wsp += (size_t)N * 4;
  uint2* epack = (uint2*)wsp;         wsp += (size_t)E * 8;
  unsigned* bincnt = (unsigned*)wsp;  wsp += 128 * 4;
  float* stats = (float*)wsp;         wsp += 128 * 4;
  unsigned* binbase = (unsigned*)wsp; wsp += 132 * 4;
  unsigned* bincur = (unsigned*)wsp;  wsp += 128 * 4;

  uint2* binbuf = (uint2*)hf;  // aliases hf: dead until layer_kernel<0> writes it

  const unsigned short* frag_t = frags;
  const unsigned short* frag_i = frags + 2 * 12288;
  const unsigned short* frag_h = frags + 4 * 12288;

  hipMemsetAsync(bincnt, 0, 256 * 4, stream);  // bincnt + stats (adjacent)

  wprep_kernel<<<18, 256, 0, stream>>>(W, w_ih, w_hh, frags);
  conv_bf16_kernel<<<(N * 16 + 255) / 256, 256, 0, stream>>>(h, xbf0, N * 16);

  // CSR: histogram -> bin scan -> binned scatter -> per-bin (dst,rel) sort
  histo_kernel<<<(E + 2047) / 2048, 256, 0, stream>>>(dst, bincnt, E);
  scan128_kernel<<<1, 128, 0, stream>>>(bincnt, binbase, bincur, offs, NBINS, N);
  bin_scatter_kernel<<<(E + SCHUNK - 1) / SCHUNK, 256, 0, stream>>>(
      src, dst, rel, norm, bincur, binbuf, E);
  bin_sort_kernel<<<NBINS, 1024, 0, stream>>>(binbuf, binbase, epack, offs,
                                              rcnt, N);

  // layer 0: gather from bf16 h0; GRU (hstate=0) -> fp32 h1 + bf16 h1
  layer_kernel<0><<<NT, 256, 0, stream>>>(xbf0, nullptr, offs, rcnt, epack,
                                          frag_t, frag_i, frag_h, b_ih, b_hh,
                                          hf, xbf1, nullptr, N);
  // layer 1: gather from bf16 h1; GRU h-path from fp32 h1 -> out + BN stats
  layer_kernel<1><<<NT, 256, 0, stream>>>(xbf1, hf, offs, rcnt, epack,
                                          frag_t, frag_i, frag_h, b_ih, b_hh,
                                          out, nullptr, stats, N);

  int total = N * 64;
  bn_apply_kernel<<<(total + 255) / 256, 256, 0, stream>>>(out, stats, gamma,
                                                           beta, N, total);
}

// Round 19
// 307.391 us; speedup vs baseline: 1.5401x; 1.5401x over previous
//
#include <hip/hip_runtime.h>

typedef __bf16 bf16x8 __attribute__((ext_vector_type(8)));
typedef float f32x4 __attribute__((ext_vector_type(4)));
typedef short short8 __attribute__((ext_vector_type(8)));

#define MFMA16(a, b, c) __builtin_amdgcn_mfma_f32_16x16x32_bf16(a, b, c, 0, 0, 0)

__device__ inline unsigned short bf16_rne(float x) {
  unsigned u = __builtin_bit_cast(unsigned, x);
  return (unsigned short)((u + 0x7FFFu + ((u >> 16) & 1u)) >> 16);
}
__device__ inline float bf16_tof(unsigned short s) {
  unsigned u = ((unsigned)s) << 16;
  return __builtin_bit_cast(float, u);
}
__device__ inline void split2(float x, unsigned short* hi, unsigned short* lo) {
  unsigned short h = bf16_rne(x);
  *hi = h;
  *lo = bf16_rne(x - bf16_tof(h));
}
__device__ inline float fast_rcp(float x) { return __builtin_amdgcn_rcpf(x); }

// ---------------- weight frag prep ----------------
// set0 (Wcat, K=192): ((tci*6+ks)*64+lane)*8+j, hi frags[0], lo frags[12288].
// set1 (w_ih) / set2 (w_hh): 12 col-tiles x 2 k-chunks at (2+2*set)*12288.

__global__ __launch_bounds__(256) void wprep_kernel(
    const float* __restrict__ W, const float* __restrict__ w_ih,
    const float* __restrict__ w_hh, unsigned short* __restrict__ frags) {
  int idx = blockIdx.x * 256 + threadIdx.x;
  if (idx < 1536) {
    int lane = idx & 63;
    int ks = (idx >> 6) % 6;
    int tci = idx / (6 * 64);
    int c = tci * 16 + (lane & 15);
    size_t dbase = ((size_t)(tci * 6 + ks) * 64 + lane) * 8;
#pragma unroll
    for (int j = 0; j < 8; ++j) {
      int k = ks * 32 + ((lane >> 4) << 3) + j;  // 0..191
      int r = k >> 6, d = k & 63;
      float v = W[(r << 12) + (d << 6) + c];
      unsigned short h, l;
      split2(v, &h, &l);
      frags[dbase + j] = h;
      frags[12288 + dbase + j] = l;
    }
  } else if (idx < 1536 + 2 * 1536) {
    int i2 = idx - 1536;
    int set = i2 / 1536;
    int i3 = i2 % 1536;
    int lane = i3 & 63;
    int ks = (i3 >> 6) & 1;
    int tci = (i3 >> 7) % 12;
    int c = tci * 16 + (lane & 15);
    unsigned short* hi = frags + (size_t)(2 + 2 * set) * 12288;
    unsigned short* lo = hi + 12288;
    size_t dbase = ((size_t)(tci * 2 + ks) * 64 + lane) * 8;
    const float* wsrc = set ? w_hh : w_ih;
#pragma unroll
    for (int j = 0; j < 8; ++j) {
      int k = ks * 32 + ((lane >> 4) << 3) + j;
      float v = wsrc[(c << 6) + k];
      unsigned short h, l;
      split2(v, &h, &l);
      hi[dbase + j] = h;
      lo[dbase + j] = l;
    }
  }
}

// ---------------- CSR build ----------------

__global__ __launch_bounds__(256) void count_kernel(
    const int* __restrict__ dst, unsigned* __restrict__ counts, int E) {
  int base = (blockIdx.x * 256 + threadIdx.x) * 4;
  if (base + 4 <= E) {
    int4 d = *(const int4*)(dst + base);
    atomicAdd(&counts[d.x], 1u);
    atomicAdd(&counts[d.y], 1u);
    atomicAdd(&counts[d.z], 1u);
    atomicAdd(&counts[d.w], 1u);
  } else {
    for (int k = base; k < E; ++k) atomicAdd(&counts[dst[k]], 1u);
  }
}

__global__ __launch_bounds__(1024) void scan_k1(
    const unsigned* __restrict__ counts, unsigned* __restrict__ offs,
    unsigned* __restrict__ bsums, int N) {
  __shared__ unsigned sm[1024];
  int tid = threadIdx.x;
  int i = blockIdx.x * 1024 + tid;
  unsigned v = (i < N) ? counts[i] : 0u;
  sm[tid] = v;
  __syncthreads();
  for (int ofs = 1; ofs < 1024; ofs <<= 1) {
    unsigned add = (tid >= ofs) ? sm[tid - ofs] : 0u;
    __syncthreads();
    sm[tid] += add;
    __syncthreads();
  }
  if (i < N) offs[i] = sm[tid] - v;
  if (tid == 0) bsums[blockIdx.x] = sm[1023];
}

__global__ __launch_bounds__(128) void scan_k2(
    unsigned* __restrict__ bsums, unsigned* __restrict__ offs, int M, int N) {
  __shared__ unsigned sm[128];
  int tid = threadIdx.x;
  unsigned v = (tid < M) ? bsums[tid] : 0u;
  sm[tid] = v;
  __syncthreads();
  for (int ofs = 1; ofs < 128; ofs <<= 1) {
    unsigned add = (tid >= ofs) ? sm[tid - ofs] : 0u;
    __syncthreads();
    sm[tid] += add;
    __syncthreads();
  }
  if (tid < M) bsums[tid] = sm[tid] - v;
  if (tid == 127) offs[N] = sm[127];
}

__global__ __launch_bounds__(256) void scan_k3(
    unsigned* __restrict__ offs, const unsigned* __restrict__ bsums, int N) {
  int i = blockIdx.x * 256 + threadIdx.x;
  if (i < N) offs[i] = offs[i] + bsums[i >> 10];
}

__global__ __launch_bounds__(128) void bin_init_kernel(
    const unsigned* __restrict__ offs, unsigned* __restrict__ bincur, int nbins) {
  int b = threadIdx.x;
  if (b < nbins) bincur[b] = offs[b << 10];
}

// pass 1: block-aggregated scatter into dst-bins.
#define SCHUNK 2048
__global__ __launch_bounds__(256) void bin_scatter_kernel(
    const int* __restrict__ src, const int* __restrict__ dst,
    const int* __restrict__ rel, const float* __restrict__ norm,
    unsigned* __restrict__ bincur, uint2* __restrict__ binbuf, int E) {
  __shared__ unsigned cnt[128];
  __shared__ unsigned base[128];
  int tid = threadIdx.x;
  int start = blockIdx.x * SCHUNK;
  if (tid < 128) cnt[tid] = 0u;
  __syncthreads();
  unsigned mybin[8];
  uint2 myrec[8];
#pragma unroll
  for (int i = 0; i < 8; ++i) {
    int e = start + i * 256 + tid;
    if (e < E) {
      int d = dst[e];
      mybin[i] = (unsigned)d >> 10;
      myrec[i].x = (unsigned)src[e] | ((unsigned)rel[e] << 17) |
                   ((unsigned)(d & 1023) << 19);
      myrec[i].y = __builtin_bit_cast(unsigned, norm[e]);
      atomicAdd(&cnt[mybin[i]], 1u);
    } else {
      mybin[i] = 0xFFFFFFFFu;
    }
  }
  __syncthreads();
  if (tid < 128) {
    unsigned c = cnt[tid];
    base[tid] = c ? atomicAdd(&bincur[tid], c) : 0u;
    cnt[tid] = 0u;
  }
  __syncthreads();
#pragma unroll
  for (int i = 0; i < 8; ++i) {
    if (mybin[i] != 0xFFFFFFFFu) {
      unsigned r = atomicAdd(&cnt[mybin[i]], 1u);
      binbuf[base[mybin[i]] + r] = myrec[i];
    }
  }
}

// pass 2: per-bin counting sort by (dst, rel); emits per-node run lengths rcnt.
__global__ __launch_bounds__(1024) void bin_sort_kernel(
    const uint2* __restrict__ binbuf, const unsigned* __restrict__ offs,
    uint2* __restrict__ epack, unsigned* __restrict__ rcnt, int N) {
  __shared__ unsigned cnt[3 * 1024];  // per (rel, dlo) counts -> cursors
  __shared__ unsigned offl[1024];
  int bin = blockIdx.x;
  int base = bin << 10;
  int tid = threadIdx.x;
  int hi = base + 1024;
  if (hi > N) hi = N;
  if (base + tid < N) offl[tid] = offs[base + tid];
  cnt[tid] = 0u;
  cnt[1024 + tid] = 0u;
  cnt[2048 + tid] = 0u;
  __syncthreads();
  unsigned start = offs[base];
  unsigned end = offs[hi];
  for (unsigned j = start + tid; j < end; j += 1024) {
    uint2 rec = binbuf[j];
    unsigned dlo = rec.x >> 19;
    unsigned r = (rec.x >> 17) & 3;
    atomicAdd(&cnt[r * 1024 + dlo], 1u);
  }
  __syncthreads();
  unsigned c0 = cnt[tid], c1 = cnt[1024 + tid];
  int n = base + tid;
  if (n < N) rcnt[n] = c0 | (c1 << 16);
  unsigned o = (n < N) ? offl[tid] : 0u;
  cnt[tid] = o;
  cnt[1024 + tid] = o + c0;
  cnt[2048 + tid] = o + c0 + c1;
  __syncthreads();
  for (unsigned j = start + tid; j < end; j += 1024) {
    uint2 rec = binbuf[j];
    unsigned dlo = rec.x >> 19;
    unsigned r = (rec.x >> 17) & 3;
    unsigned p = atomicAdd(&cnt[r * 1024 + dlo], 1u);
    epack[p] = rec;
  }
}

// ---------------- fused layer: gather + Wcat-GEMM + GRU ----------------
// Per block: 16 nodes. Phase 1 gathers z[3][64] (rel-sorted runs, fp32).
// Phase 2: K=192 split-bf16 MFMA -> swh tile (LDS). Phase 3: GRU MFMAs +
// register gates; LAYER=0 writes fp32 h1, LAYER=1 reads hf rows for the
// h-path (split in-kernel) and hp (exact fp32), writes fp32 out.

template <int LAYER>
__global__ __launch_bounds__(256) void layer_kernel(
    const float* __restrict__ xf, const unsigned* __restrict__ offs,
    const unsigned* __restrict__ rcnt, const uint2* __restrict__ epack,
    const unsigned short* __restrict__ wft,
    const unsigned short* __restrict__ wfi, const unsigned short* __restrict__ wfh,
    const float* __restrict__ b_ih, const float* __restrict__ b_hh,
    float* __restrict__ outf, int N) {
  __shared__ float zld[16][197];
  __shared__ float swht[16][69];
  int tid = threadIdx.x;
  int n0 = blockIdx.x << 4;

  // ---- phase 1: gather (one 16-lane group per node; rel runs) ----
  {
    int g = tid >> 4, l16 = tid & 15;
    int n = n0 + g;
    int c4 = l16 << 2;
    float z0[4] = {}, z1[4] = {}, z2[4] = {};
    if (n < N) {
      unsigned a = offs[n], b = offs[n + 1];
      unsigned rc = rcnt[n];
      unsigned b1 = a + (rc & 0xFFFFu), b2 = b1 + (rc >> 16);
      auto run = [&](unsigned s, unsigned e, float* z) {
        unsigned j = s;
        for (; j + 2 <= e; j += 2) {
          uint2 e0 = epack[j], e1 = epack[j + 1];
          float4 v0 = *(const float4*)(xf + (((size_t)(e0.x & 0x1FFFFu)) << 6) + c4);
          float4 v1 = *(const float4*)(xf + (((size_t)(e1.x & 0x1FFFFu)) << 6) + c4);
          float nv0 = __builtin_bit_cast(float, e0.y);
          float nv1 = __builtin_bit_cast(float, e1.y);
          z[0] = fmaf(nv0, v0.x, fmaf(nv1, v1.x, z[0]));
          z[1] = fmaf(nv0, v0.y, fmaf(nv1, v1.y, z[1]));
          z[2] = fmaf(nv0, v0.z, fmaf(nv1, v1.z, z[2]));
          z[3] = fmaf(nv0, v0.w, fmaf(nv1, v1.w, z[3]));
        }
        if (j < e) {
          uint2 e0 = epack[j];
          float4 v0 = *(const float4*)(xf + (((size_t)(e0.x & 0x1FFFFu)) << 6) + c4);
          float nv0 = __builtin_bit_cast(float, e0.y);
          z[0] = fmaf(nv0, v0.x, z[0]);
          z[1] = fmaf(nv0, v0.y, z[1]);
          z[2] = fmaf(nv0, v0.z, z[2]);
          z[3] = fmaf(nv0, v0.w, z[3]);
        }
      };
      run(a, b1, z0);
      run(b1, b2, z1);
      run(b2, b, z2);
    }
#pragma unroll
    for (int i = 0; i < 4; ++i) {
      zld[g][c4 + i] = z0[i];
      zld[g][64 + c4 + i] = z1[i];
      zld[g][128 + c4 + i] = z2[i];
    }
  }
  __syncthreads();

  // ---- phase 2: z @ Wcat (K=192) -> swht ----
  int lane = tid & 63, w = tid >> 6;
  int r15 = lane & 15, kq = lane >> 4;
  {
    const short8* fh = (const short8*)wft;
    const short8* fl = (const short8*)(wft + 12288);
    f32x4 acc = {0.f, 0.f, 0.f, 0.f};
#pragma unroll
    for (int ks = 0; ks < 6; ++ks) {
      const float* zr = &zld[r15][ks * 32 + (kq << 3)];
      short8 th, tl;
#pragma unroll
      for (int jj = 0; jj < 8; ++jj) {
        unsigned short h_, l_;
        split2(zr[jj], &h_, &l_);
        th[jj] = (short)h_;
        tl[jj] = (short)l_;
      }
      bf16x8 ahi = __builtin_bit_cast(bf16x8, th);
      bf16x8 alo = __builtin_bit_cast(bf16x8, tl);
      bf16x8 bhi = __builtin_bit_cast(bf16x8, fh[(w * 6 + ks) * 64 + lane]);
      bf16x8 blo = __builtin_bit_cast(bf16x8, fl[(w * 6 + ks) * 64 + lane]);
      acc = MFMA16(ahi, bhi, acc);
      acc = MFMA16(ahi, blo, acc);
      acc = MFMA16(alo, bhi, acc);
    }
    int c = (w << 4) + r15;
#pragma unroll
    for (int reg = 0; reg < 4; ++reg) swht[(kq << 2) + reg][c] = acc[reg];
  }
  __syncthreads();

  // ---- phase 3: GRU ----
  {
    int c = (w << 4) + r15;
    int row = n0 + r15;
    if (row >= N) row = N - 1;

    bf16x8 axh[2], axl[2], ahh2[2], ahl2[2];
#pragma unroll
    for (int ks = 0; ks < 2; ++ks) {
      const float* sr = &swht[r15][(ks << 5) + (kq << 3)];
      short8 th, tl;
#pragma unroll
      for (int jj = 0; jj < 8; ++jj) {
        unsigned short h_, l_;
        split2(sr[jj], &h_, &l_);
        th[jj] = (short)h_;
        tl[jj] = (short)l_;
      }
      axh[ks] = __builtin_bit_cast(bf16x8, th);
      axl[ks] = __builtin_bit_cast(bf16x8, tl);
    }
    if (LAYER) {
#pragma unroll
      for (int ks = 0; ks < 2; ++ks) {
        const float* hr = xf + (((size_t)row) << 6) + ks * 32 + (kq << 3);
        float4 h0 = *(const float4*)hr;
        float4 h1v = *(const float4*)(hr + 4);
        float hv[8] = {h0.x, h0.y, h0.z, h0.w, h1v.x, h1v.y, h1v.z, h1v.w};
        short8 th, tl;
#pragma unroll
        for (int jj = 0; jj < 8; ++jj) {
          unsigned short h_, l_;
          split2(hv[jj], &h_, &l_);
          th[jj] = (short)h_;
          tl[jj] = (short)l_;
        }
        ahh2[ks] = __builtin_bit_cast(bf16x8, th);
        ahl2[ks] = __builtin_bit_cast(bf16x8, tl);
      }
    }

    const short8* fih = (const short8*)wfi;
    const short8* fil = (const short8*)(wfi + 12288);
    const short8* fhh = (const short8*)wfh;
    const short8* fhl = (const short8*)(wfh + 12288);
    f32x4 accx[3], acch[3];
#pragma unroll
    for (int g = 0; g < 3; ++g) {
      accx[g] = (f32x4){0.f, 0.f, 0.f, 0.f};
      acch[g] = (f32x4){0.f, 0.f, 0.f, 0.f};
#pragma unroll
      for (int ks = 0; ks < 2; ++ks) {
        int tci = (g << 2) + w;
        bf16x8 bih = __builtin_bit_cast(bf16x8, fih[(tci * 2 + ks) * 64 + lane]);
        bf16x8 bil = __builtin_bit_cast(bf16x8, fil[(tci * 2 + ks) * 64 + lane]);
        accx[g] = MFMA16(axh[ks], bih, accx[g]);
        accx[g] = MFMA16(axh[ks], bil, accx[g]);
        accx[g] = MFMA16(axl[ks], bih, accx[g]);
        if (LAYER) {
          bf16x8 bhh = __builtin_bit_cast(bf16x8, fhh[(tci * 2 + ks) * 64 + lane]);
          bf16x8 bhl = __builtin_bit_cast(bf16x8, fhl[(tci * 2 + ks) * 64 + lane]);
          acch[g] = MFMA16(ahh2[ks], bhh, acch[g]);
          acch[g] = MFMA16(ahh2[ks], bhl, acch[g]);
          acch[g] = MFMA16(ahl2[ks], bhh, acch[g]);
        }
      }
    }

    float bi0 = b_ih[c], bi1 = b_ih[64 + c], bi2 = b_ih[128 + c];
    float bh0 = b_hh[c], bh1 = b_hh[64 + c], bh2 = b_hh[128 + c];
#pragma unroll
    for (int reg = 0; reg < 4; ++reg) {
      int n = n0 + (kq << 2) + reg;
      if (n >= N) break;
      size_t idx = (((size_t)n) << 6) + c;
      float hp = LAYER ? xf[idx] : 0.f;
      float gir = accx[0][reg] + bi0;
      float giz = accx[1][reg] + bi1;
      float gin = accx[2][reg] + bi2;
      float ghr = (LAYER ? acch[0][reg] : 0.f) + bh0;
      float ghz = (LAYER ? acch[1][reg] : 0.f) + bh1;
      float ghn = (LAYER ? acch[2][reg] : 0.f) + bh2;
      float r = fast_rcp(1.f + __expf(-(gir + ghr)));
      float z = fast_rcp(1.f + __expf(-(giz + ghz)));
      float nn = 1.f - 2.f * fast_rcp(1.f + __expf(2.f * (gin + r * ghn)));
      outf[idx] = (1.f - z) * nn + z * hp;
    }
  }
}

// ---------------- batchnorm ----------------

__global__ __launch_bounds__(256) void bn_stats_kernel(
    const float* __restrict__ h, float* __restrict__ stats, int N) {
  int tid = threadIdx.x;
  int c = tid & 63;
  float s = 0.f, ss = 0.f;
  for (int n = blockIdx.x * 4 + (tid >> 6); n < N; n += gridDim.x * 4) {
    float v = h[(size_t)n * 64 + c];
    s += v;
    ss += v * v;
  }
  __shared__ float sm[2][256];
  sm[0][tid] = s;
  sm[1][tid] = ss;
  __syncthreads();
  if (tid < 64) {
    s = sm[0][tid] + sm[0][tid + 64] + sm[0][tid + 128] + sm[0][tid + 192];
    ss = sm[1][tid] + sm[1][tid + 64] + sm[1][tid + 128] + sm[1][tid + 192];
    atomicAdd(&stats[tid], s);
    atomicAdd(&stats[64 + tid], ss);
  }
}

__global__ __launch_bounds__(256) void bn_apply_kernel(
    float* out, const float* __restrict__ stats,
    const float* __restrict__ gamma, const float* __restrict__ beta,
    int N, int total) {
  int idx = blockIdx.x * 256 + threadIdx.x;
  if (idx >= total) return;
  int c = idx & 63;
  float invN = 1.f / (float)N;
  float mean = stats[c] * invN;
  float var = stats[64 + c] * invN - mean * mean;
  float sc = rsqrtf(var + 1e-5f) * gamma[c];
  float sh = beta[c] - mean * sc;
  out[idx] = out[idx] * sc + sh;
}

// ---------------- launch ----------------

extern "C" void kernel_launch(void* const* d_in, const int* in_sizes, int n_in,
                              void* d_out, int out_size, void* d_ws, size_t ws_size,
                              hipStream_t stream) {
  const float* h     = (const float*)d_in[0];
  const float* norm  = (const float*)d_in[1];
  const float* W     = (const float*)d_in[2];
  const float* w_ih  = (const float*)d_in[3];
  const float* w_hh  = (const float*)d_in[4];
  const float* b_ih  = (const float*)d_in[5];
  const float* b_hh  = (const float*)d_in[6];
  const float* gamma = (const float*)d_in[7];
  const float* beta  = (const float*)d_in[8];
  const int* src     = (const int*)d_in[9];
  const int* dst     = (const int*)d_in[10];
  const int* rel     = (const int*)d_in[11];
  float* out = (float*)d_out;

  const int N = in_sizes[0] / 64;
  const int E = in_sizes[1];
  const int NT = (N + 15) / 16;
  const int NBINS = (N + 1023) / 1024;

  char* wsp = (char*)d_ws;
  float* hf = (float*)wsp;                      wsp += (size_t)N * 64 * 4;  // fp32 h1
  unsigned short* frags = (unsigned short*)wsp; wsp += 6 * 12288 * 2;
  unsigned* offs = (unsigned*)wsp;   wsp += ((size_t)N + 4) * 4;
  unsigned* cursor = (unsigned*)wsp; wsp += (size_t)N * 4;
  unsigned* rcnt = (unsigned*)wsp;   wsp += (size_t)N * 4;
  uint2* epack = (uint2*)wsp;        wsp += (size_t)E * 8;
  unsigned* bsums = (unsigned*)wsp;  wsp += 128 * 4;
  float* stats = (float*)wsp;        wsp += 128 * 4;

  uint2* binbuf = (uint2*)hf;  // aliases hf: dead until layer_kernel<0> writes it
  unsigned* bincur = cursor;   // reuse counter buffer (dead after scan)

  const unsigned short* frag_t = frags;
  const unsigned short* frag_i = frags + 2 * 12288;
  const unsigned short* frag_h = frags + 4 * 12288;

  const int M = (N + 1023) / 1024;

  hipMemsetAsync(cursor, 0, (size_t)N * 4, stream);
  hipMemsetAsync(stats, 0, 128 * 4, stream);

  wprep_kernel<<<18, 256, 0, stream>>>(W, w_ih, w_hh, frags);

  // CSR over dst (graph is layer-invariant): count -> scan -> (dst,rel) sort
  count_kernel<<<(E / 4 + 255) / 256, 256, 0, stream>>>(dst, cursor, E);
  scan_k1<<<M, 1024, 0, stream>>>(cursor, offs, bsums, N);
  scan_k2<<<1, 128, 0, stream>>>(bsums, offs, M, N);
  scan_k3<<<(N + 255) / 256, 256, 0, stream>>>(offs, bsums, N);
  bin_init_kernel<<<1, 128, 0, stream>>>(offs, bincur, NBINS);
  bin_scatter_kernel<<<(E + SCHUNK - 1) / SCHUNK, 256, 0, stream>>>(
      src, dst, rel, norm, bincur, binbuf, E);
  bin_sort_kernel<<<NBINS, 1024, 0, stream>>>(binbuf, offs, epack, rcnt, N);

  // layer 0: gather from input h; GRU (hstate=0) -> fp32 h1
  layer_kernel<0><<<NT, 256, 0, stream>>>(h, offs, rcnt, epack, frag_t,
                                          frag_i, frag_h, b_ih, b_hh, hf, N);
  // layer 1: gather from h1; GRU (h-path from h1) -> fp32 out
  layer_kernel<1><<<NT, 256, 0, stream>>>(hf, offs, rcnt, epack, frag_t,
                                          frag_i, frag_h, b_ih, b_hh, out, N);

  bn_stats_kernel<<<256, 256, 0, stream>>>(out, stats, N);
  int total = N * 64;
  bn_apply_kernel<<<(total + 255) / 256, 256, 0, stream>>>(out, stats, gamma,
                                                           beta, N, total);
}

// Round 20
// 303.667 us; speedup vs baseline: 1.5590x; 1.0123x over previous
//
#include <hip/hip_runtime.h>

typedef __bf16 bf16x8 __attribute__((ext_vector_type(8)));
typedef float f32x4 __attribute__((ext_vector_type(4)));
typedef short short8 __attribute__((ext_vector_type(8)));

#define MFMA16(a, b, c) __builtin_amdgcn_mfma_f32_16x16x32_bf16(a, b, c, 0, 0, 0)

__device__ inline unsigned short bf16_rne(float x) {
  unsigned u = __builtin_bit_cast(unsigned, x);
  return (unsigned short)((u + 0x7FFFu + ((u >> 16) & 1u)) >> 16);
}
__device__ inline float bf16_tof(unsigned short s) {
  unsigned u = ((unsigned)s) << 16;
  return __builtin_bit_cast(float, u);
}
__device__ inline void split2(float x, unsigned short* hi, unsigned short* lo) {
  unsigned short h = bf16_rne(x);
  *hi = h;
  *lo = bf16_rne(x - bf16_tof(h));
}
__device__ inline float fast_rcp(float x) { return __builtin_amdgcn_rcpf(x); }

// ---------------- weight frag prep ----------------
// set0 (Wcat, K=192): ((tci*6+ks)*64+lane)*8+j, hi frags[0], lo frags[12288].
// set1 (w_ih) / set2 (w_hh): 12 col-tiles x 2 k-chunks at (2+2*set)*12288.

__global__ __launch_bounds__(256) void wprep_kernel(
    const float* __restrict__ W, const float* __restrict__ w_ih,
    const float* __restrict__ w_hh, unsigned short* __restrict__ frags) {
  int idx = blockIdx.x * 256 + threadIdx.x;
  if (idx < 1536) {
    int lane = idx & 63;
    int ks = (idx >> 6) % 6;
    int tci = idx / (6 * 64);
    int c = tci * 16 + (lane & 15);
    size_t dbase = ((size_t)(tci * 6 + ks) * 64 + lane) * 8;
#pragma unroll
    for (int j = 0; j < 8; ++j) {
      int k = ks * 32 + ((lane >> 4) << 3) + j;  // 0..191
      int r = k >> 6, d = k & 63;
      float v = W[(r << 12) + (d << 6) + c];
      unsigned short h, l;
      split2(v, &h, &l);
      frags[dbase + j] = h;
      frags[12288 + dbase + j] = l;
    }
  } else if (idx < 1536 + 2 * 1536) {
    int i2 = idx - 1536;
    int set = i2 / 1536;
    int i3 = i2 % 1536;
    int lane = i3 & 63;
    int ks = (i3 >> 6) & 1;
    int tci = (i3 >> 7) % 12;
    int c = tci * 16 + (lane & 15);
    unsigned short* hi = frags + (size_t)(2 + 2 * set) * 12288;
    unsigned short* lo = hi + 12288;
    size_t dbase = ((size_t)(tci * 2 + ks) * 64 + lane) * 8;
    const float* wsrc = set ? w_hh : w_ih;
#pragma unroll
    for (int j = 0; j < 8; ++j) {
      int k = ks * 32 + ((lane >> 4) << 3) + j;
      float v = wsrc[(c << 6) + k];
      unsigned short h, l;
      split2(v, &h, &l);
      hi[dbase + j] = h;
      lo[dbase + j] = l;
    }
  }
}

// ---------------- CSR build ----------------

__global__ __launch_bounds__(256) void count_kernel(
    const int* __restrict__ dst, unsigned* __restrict__ counts, int E) {
  int base = (blockIdx.x * 256 + threadIdx.x) * 4;
  if (base + 4 <= E) {
    int4 d = *(const int4*)(dst + base);
    atomicAdd(&counts[d.x], 1u);
    atomicAdd(&counts[d.y], 1u);
    atomicAdd(&counts[d.z], 1u);
    atomicAdd(&counts[d.w], 1u);
  } else {
    for (int k = base; k < E; ++k) atomicAdd(&counts[dst[k]], 1u);
  }
}

__global__ __launch_bounds__(1024) void scan_k1(
    const unsigned* __restrict__ counts, unsigned* __restrict__ offs,
    unsigned* __restrict__ bsums, int N) {
  __shared__ unsigned sm[1024];
  int tid = threadIdx.x;
  int i = blockIdx.x * 1024 + tid;
  unsigned v = (i < N) ? counts[i] : 0u;
  sm[tid] = v;
  __syncthreads();
  for (int ofs = 1; ofs < 1024; ofs <<= 1) {
    unsigned add = (tid >= ofs) ? sm[tid - ofs] : 0u;
    __syncthreads();
    sm[tid] += add;
    __syncthreads();
  }
  if (i < N) offs[i] = sm[tid] - v;
  if (tid == 0) bsums[blockIdx.x] = sm[1023];
}

__global__ __launch_bounds__(128) void scan_k2(
    unsigned* __restrict__ bsums, unsigned* __restrict__ offs, int M, int N) {
  __shared__ unsigned sm[128];
  int tid = threadIdx.x;
  unsigned v = (tid < M) ? bsums[tid] : 0u;
  sm[tid] = v;
  __syncthreads();
  for (int ofs = 1; ofs < 128; ofs <<= 1) {
    unsigned add = (tid >= ofs) ? sm[tid - ofs] : 0u;
    __syncthreads();
    sm[tid] += add;
    __syncthreads();
  }
  if (tid < M) bsums[tid] = sm[tid] - v;
  if (tid == 127) offs[N] = sm[127];
}

__global__ __launch_bounds__(256) void scan_k3(
    unsigned* __restrict__ offs, const unsigned* __restrict__ bsums, int N) {
  int i = blockIdx.x * 256 + threadIdx.x;
  if (i < N) offs[i] = offs[i] + bsums[i >> 10];
}

__global__ __launch_bounds__(128) void bin_init_kernel(
    const unsigned* __restrict__ offs, unsigned* __restrict__ bincur, int nbins) {
  int b = threadIdx.x;
  if (b < nbins) bincur[b] = offs[b << 10];
}

// pass 1: block-aggregated scatter into dst-bins.
#define SCHUNK 2048
__global__ __launch_bounds__(256) void bin_scatter_kernel(
    const int* __restrict__ src, const int* __restrict__ dst,
    const int* __restrict__ rel, const float* __restrict__ norm,
    unsigned* __restrict__ bincur, uint2* __restrict__ binbuf, int E) {
  __shared__ unsigned cnt[128];
  __shared__ unsigned base[128];
  int tid = threadIdx.x;
  int start = blockIdx.x * SCHUNK;
  if (tid < 128) cnt[tid] = 0u;
  __syncthreads();
  unsigned mybin[8];
  uint2 myrec[8];
#pragma unroll
  for (int i = 0; i < 8; ++i) {
    int e = start + i * 256 + tid;
    if (e < E) {
      int d = dst[e];
      mybin[i] = (unsigned)d >> 10;
      myrec[i].x = (unsigned)src[e] | ((unsigned)rel[e] << 17) |
                   ((unsigned)(d & 1023) << 19);
      myrec[i].y = __builtin_bit_cast(unsigned, norm[e]);
      atomicAdd(&cnt[mybin[i]], 1u);
    } else {
      mybin[i] = 0xFFFFFFFFu;
    }
  }
  __syncthreads();
  if (tid < 128) {
    unsigned c = cnt[tid];
    base[tid] = c ? atomicAdd(&bincur[tid], c) : 0u;
    cnt[tid] = 0u;
  }
  __syncthreads();
#pragma unroll
  for (int i = 0; i < 8; ++i) {
    if (mybin[i] != 0xFFFFFFFFu) {
      unsigned r = atomicAdd(&cnt[mybin[i]], 1u);
      binbuf[base[mybin[i]] + r] = myrec[i];
    }
  }
}

// pass 2: per-bin counting sort by (dst, rel); emits per-node run lengths rcnt.
__global__ __launch_bounds__(1024) void bin_sort_kernel(
    const uint2* __restrict__ binbuf, const unsigned* __restrict__ offs,
    uint2* __restrict__ epack, unsigned* __restrict__ rcnt, int N) {
  __shared__ unsigned cnt[3 * 1024];  // per (rel, dlo) counts -> cursors
  __shared__ unsigned offl[1024];
  int bin = blockIdx.x;
  int base = bin << 10;
  int tid = threadIdx.x;
  int hi = base + 1024;
  if (hi > N) hi = N;
  if (base + tid < N) offl[tid] = offs[base + tid];
  cnt[tid] = 0u;
  cnt[1024 + tid] = 0u;
  cnt[2048 + tid] = 0u;
  __syncthreads();
  unsigned start = offs[base];
  unsigned end = offs[hi];
  for (unsigned j = start + tid; j < end; j += 1024) {
    uint2 rec = binbuf[j];
    unsigned dlo = rec.x >> 19;
    unsigned r = (rec.x >> 17) & 3;
    atomicAdd(&cnt[r * 1024 + dlo], 1u);
  }
  __syncthreads();
  unsigned c0 = cnt[tid], c1 = cnt[1024 + tid];
  int n = base + tid;
  if (n < N) rcnt[n] = c0 | (c1 << 16);
  unsigned o = (n < N) ? offl[tid] : 0u;
  cnt[tid] = o;
  cnt[1024 + tid] = o + c0;
  cnt[2048 + tid] = o + c0 + c1;
  __syncthreads();
  for (unsigned j = start + tid; j < end; j += 1024) {
    uint2 rec = binbuf[j];
    unsigned dlo = rec.x >> 19;
    unsigned r = (rec.x >> 17) & 3;
    unsigned p = atomicAdd(&cnt[r * 1024 + dlo], 1u);
    epack[p] = rec;
  }
}

// ---------------- fused layer: gather + Wcat-GEMM + GRU ----------------
// Per block: 16 nodes. Phase 1 gathers z[3][64] (rel-sorted runs, fp32),
// 4-deep unrolled inside the PROVEN lambda shape (same float* arg, constant
// z[0..3] indices; only the unroll depth differs from R12/R19).
// Phase 2: K=192 split-bf16 MFMA -> swh tile (LDS). Phase 3: GRU MFMAs +
// register gates; LAYER=0 writes fp32 h1, LAYER=1 reads hf rows for the
// h-path (split in-kernel) and hp (exact fp32), writes fp32 out.

template <int LAYER>
__global__ __launch_bounds__(256) void layer_kernel(
    const float* __restrict__ xf, const unsigned* __restrict__ offs,
    const unsigned* __restrict__ rcnt, const uint2* __restrict__ epack,
    const unsigned short* __restrict__ wft,
    const unsigned short* __restrict__ wfi, const unsigned short* __restrict__ wfh,
    const float* __restrict__ b_ih, const float* __restrict__ b_hh,
    float* __restrict__ outf, int N) {
  __shared__ float zld[16][197];
  __shared__ float swht[16][69];
  int tid = threadIdx.x;
  int n0 = blockIdx.x << 4;

  // ---- phase 1: gather (one 16-lane group per node; rel runs) ----
  {
    int g = tid >> 4, l16 = tid & 15;
    int n = n0 + g;
    int c4 = l16 << 2;
    float z0[4] = {}, z1[4] = {}, z2[4] = {};
    if (n < N) {
      unsigned a = offs[n], b = offs[n + 1];
      unsigned rc = rcnt[n];
      unsigned b1 = a + (rc & 0xFFFFu), b2 = b1 + (rc >> 16);
      auto run = [&](unsigned s, unsigned e, float* z) {
        unsigned j = s;
        for (; j + 4 <= e; j += 4) {
          uint2 e0 = epack[j], e1 = epack[j + 1];
          uint2 e2 = epack[j + 2], e3 = epack[j + 3];
          float4 v0 = *(const float4*)(xf + (((size_t)(e0.x & 0x1FFFFu)) << 6) + c4);
          float4 v1 = *(const float4*)(xf + (((size_t)(e1.x & 0x1FFFFu)) << 6) + c4);
          float4 v2 = *(const float4*)(xf + (((size_t)(e2.x & 0x1FFFFu)) << 6) + c4);
          float4 v3 = *(const float4*)(xf + (((size_t)(e3.x & 0x1FFFFu)) << 6) + c4);
          float nv0 = __builtin_bit_cast(float, e0.y);
          float nv1 = __builtin_bit_cast(float, e1.y);
          float nv2 = __builtin_bit_cast(float, e2.y);
          float nv3 = __builtin_bit_cast(float, e3.y);
          z[0] = fmaf(nv0, v0.x, fmaf(nv1, v1.x, fmaf(nv2, v2.x, fmaf(nv3, v3.x, z[0]))));
          z[1] = fmaf(nv0, v0.y, fmaf(nv1, v1.y, fmaf(nv2, v2.y, fmaf(nv3, v3.y, z[1]))));
          z[2] = fmaf(nv0, v0.z, fmaf(nv1, v1.z, fmaf(nv2, v2.z, fmaf(nv3, v3.z, z[2]))));
          z[3] = fmaf(nv0, v0.w, fmaf(nv1, v1.w, fmaf(nv2, v2.w, fmaf(nv3, v3.w, z[3]))));
        }
        for (; j + 2 <= e; j += 2) {
          uint2 e0 = epack[j], e1 = epack[j + 1];
          float4 v0 = *(const float4*)(xf + (((size_t)(e0.x & 0x1FFFFu)) << 6) + c4);
          float4 v1 = *(const float4*)(xf + (((size_t)(e1.x & 0x1FFFFu)) << 6) + c4);
          float nv0 = __builtin_bit_cast(float, e0.y);
          float nv1 = __builtin_bit_cast(float, e1.y);
          z[0] = fmaf(nv0, v0.x, fmaf(nv1, v1.x, z[0]));
          z[1] = fmaf(nv0, v0.y, fmaf(nv1, v1.y, z[1]));
          z[2] = fmaf(nv0, v0.z, fmaf(nv1, v1.z, z[2]));
          z[3] = fmaf(nv0, v0.w, fmaf(nv1, v1.w, z[3]));
        }
        if (j < e) {
          uint2 e0 = epack[j];
          float4 v0 = *(const float4*)(xf + (((size_t)(e0.x & 0x1FFFFu)) << 6) + c4);
          float nv0 = __builtin_bit_cast(float, e0.y);
          z[0] = fmaf(nv0, v0.x, z[0]);
          z[1] = fmaf(nv0, v0.y, z[1]);
          z[2] = fmaf(nv0, v0.z, z[2]);
          z[3] = fmaf(nv0, v0.w, z[3]);
        }
      };
      run(a, b1, z0);
      run(b1, b2, z1);
      run(b2, b, z2);
    }
#pragma unroll
    for (int i = 0; i < 4; ++i) {
      zld[g][c4 + i] = z0[i];
      zld[g][64 + c4 + i] = z1[i];
      zld[g][128 + c4 + i] = z2[i];
    }
  }
  __syncthreads();

  // ---- phase 2: z @ Wcat (K=192) -> swht ----
  int lane = tid & 63, w = tid >> 6;
  int r15 = lane & 15, kq = lane >> 4;
  {
    const short8* fh = (const short8*)wft;
    const short8* fl = (const short8*)(wft + 12288);
    f32x4 acc = {0.f, 0.f, 0.f, 0.f};
#pragma unroll
    for (int ks = 0; ks < 6; ++ks) {
      const float* zr = &zld[r15][ks * 32 + (kq << 3)];
      short8 th, tl;
#pragma unroll
      for (int jj = 0; jj < 8; ++jj) {
        unsigned short h_, l_;
        split2(zr[jj], &h_, &l_);
        th[jj] = (short)h_;
        tl[jj] = (short)l_;
      }
      bf16x8 ahi = __builtin_bit_cast(bf16x8, th);
      bf16x8 alo = __builtin_bit_cast(bf16x8, tl);
      bf16x8 bhi = __builtin_bit_cast(bf16x8, fh[(w * 6 + ks) * 64 + lane]);
      bf16x8 blo = __builtin_bit_cast(bf16x8, fl[(w * 6 + ks) * 64 + lane]);
      acc = MFMA16(ahi, bhi, acc);
      acc = MFMA16(ahi, blo, acc);
      acc = MFMA16(alo, bhi, acc);
    }
    int c = (w << 4) + r15;
#pragma unroll
    for (int reg = 0; reg < 4; ++reg) swht[(kq << 2) + reg][c] = acc[reg];
  }
  __syncthreads();

  // ---- phase 3: GRU ----
  {
    int c = (w << 4) + r15;
    int row = n0 + r15;
    if (row >= N) row = N - 1;

    bf16x8 axh[2], axl[2], ahh2[2], ahl2[2];
#pragma unroll
    for (int ks = 0; ks < 2; ++ks) {
      const float* sr = &swht[r15][(ks << 5) + (kq << 3)];
      short8 th, tl;
#pragma unroll
      for (int jj = 0; jj < 8; ++jj) {
        unsigned short h_, l_;
        split2(sr[jj], &h_, &l_);
        th[jj] = (short)h_;
        tl[jj] = (short)l_;
      }
      axh[ks] = __builtin_bit_cast(bf16x8, th);
      axl[ks] = __builtin_bit_cast(bf16x8, tl);
    }
    if (LAYER) {
#pragma unroll
      for (int ks = 0; ks < 2; ++ks) {
        const float* hr = xf + (((size_t)row) << 6) + ks * 32 + (kq << 3);
        float4 h0 = *(const float4*)hr;
        float4 h1v = *(const float4*)(hr + 4);
        float hv[8] = {h0.x, h0.y, h0.z, h0.w, h1v.x, h1v.y, h1v.z, h1v.w};
        short8 th, tl;
#pragma unroll
        for (int jj = 0; jj < 8; ++jj) {
          unsigned short h_, l_;
          split2(hv[jj], &h_, &l_);
          th[jj] = (short)h_;
          tl[jj] = (short)l_;
        }
        ahh2[ks] = __builtin_bit_cast(bf16x8, th);
        ahl2[ks] = __builtin_bit_cast(bf16x8, tl);
      }
    }

    const short8* fih = (const short8*)wfi;
    const short8* fil = (const short8*)(wfi + 12288);
    const short8* fhh = (const short8*)wfh;
    const short8* fhl = (const short8*)(wfh + 12288);
    f32x4 accx[3], acch[3];
#pragma unroll
    for (int g = 0; g < 3; ++g) {
      accx[g] = (f32x4){0.f, 0.f, 0.f, 0.f};
      acch[g] = (f32x4){0.f, 0.f, 0.f, 0.f};
#pragma unroll
      for (int ks = 0; ks < 2; ++ks) {
        int tci = (g << 2) + w;
        bf16x8 bih = __builtin_bit_cast(bf16x8, fih[(tci * 2 + ks) * 64 + lane]);
        bf16x8 bil = __builtin_bit_cast(bf16x8, fil[(tci * 2 + ks) * 64 + lane]);
        accx[g] = MFMA16(axh[ks], bih, accx[g]);
        accx[g] = MFMA16(axh[ks], bil, accx[g]);
        accx[g] = MFMA16(axl[ks], bih, accx[g]);
        if (LAYER) {
          bf16x8 bhh = __builtin_bit_cast(bf16x8, fhh[(tci * 2 + ks) * 64 + lane]);
          bf16x8 bhl = __builtin_bit_cast(bf16x8, fhl[(tci * 2 + ks) * 64 + lane]);
          acch[g] = MFMA16(ahh2[ks], bhh, acch[g]);
          acch[g] = MFMA16(ahh2[ks], bhl, acch[g]);
          acch[g] = MFMA16(ahl2[ks], bhh, acch[g]);
        }
      }
    }

    float bi0 = b_ih[c], bi1 = b_ih[64 + c], bi2 = b_ih[128 + c];
    float bh0 = b_hh[c], bh1 = b_hh[64 + c], bh2 = b_hh[128 + c];
#pragma unroll
    for (int reg = 0; reg < 4; ++reg) {
      int n = n0 + (kq << 2) + reg;
      if (n >= N) break;
      size_t idx = (((size_t)n) << 6) + c;
      float hp = LAYER ? xf[idx] : 0.f;
      float gir = accx[0][reg] + bi0;
      float giz = accx[1][reg] + bi1;
      float gin = accx[2][reg] + bi2;
      float ghr = (LAYER ? acch[0][reg] : 0.f) + bh0;
      float ghz = (LAYER ? acch[1][reg] : 0.f) + bh1;
      float ghn = (LAYER ? acch[2][reg] : 0.f) + bh2;
      float r = fast_rcp(1.f + __expf(-(gir + ghr)));
      float z = fast_rcp(1.f + __expf(-(giz + ghz)));
      float nn = 1.f - 2.f * fast_rcp(1.f + __expf(2.f * (gin + r * ghn)));
      outf[idx] = (1.f - z) * nn + z * hp;
    }
  }
}

// ---------------- batchnorm ----------------

__global__ __launch_bounds__(256) void bn_stats_kernel(
    const float* __restrict__ h, float* __restrict__ stats, int N) {
  int tid = threadIdx.x;
  int c = tid & 63;
  float s = 0.f, ss = 0.f;
  for (int n = blockIdx.x * 4 + (tid >> 6); n < N; n += gridDim.x * 4) {
    float v = h[(size_t)n * 64 + c];
    s += v;
    ss += v * v;
  }
  __shared__ float sm[2][256];
  sm[0][tid] = s;
  sm[1][tid] = ss;
  __syncthreads();
  if (tid < 64) {
    s = sm[0][tid] + sm[0][tid + 64] + sm[0][tid + 128] + sm[0][tid + 192];
    ss = sm[1][tid] + sm[1][tid + 64] + sm[1][tid + 128] + sm[1][tid + 192];
    atomicAdd(&stats[tid], s);
    atomicAdd(&stats[64 + tid], ss);
  }
}

__global__ __launch_bounds__(256) void bn_apply_kernel(
    float* out, const float* __restrict__ stats,
    const float* __restrict__ gamma, const float* __restrict__ beta,
    int N, int total) {
  int idx = blockIdx.x * 256 + threadIdx.x;
  if (idx >= total) return;
  int c = idx & 63;
  float invN = 1.f / (float)N;
  float mean = stats[c] * invN;
  float var = stats[64 + c] * invN - mean * mean;
  float sc = rsqrtf(var + 1e-5f) * gamma[c];
  float sh = beta[c] - mean * sc;
  out[idx] = out[idx] * sc + sh;
}

// ---------------- launch ----------------

extern "C" void kernel_launch(void* const* d_in, const int* in_sizes, int n_in,
                              void* d_out, int out_size, void* d_ws, size_t ws_size,
                              hipStream_t stream) {
  const float* h     = (const float*)d_in[0];
  const float* norm  = (const float*)d_in[1];
  const float* W     = (const float*)d_in[2];
  const float* w_ih  = (const float*)d_in[3];
  const float* w_hh  = (const float*)d_in[4];
  const float* b_ih  = (const float*)d_in[5];
  const float* b_hh  = (const float*)d_in[6];
  const float* gamma = (const float*)d_in[7];
  const float* beta  = (const float*)d_in[8];
  const int* src     = (const int*)d_in[9];
  const int* dst     = (const int*)d_in[10];
  const int* rel     = (const int*)d_in[11];
  float* out = (float*)d_out;

  const int N = in_sizes[0] / 64;
  const int E = in_sizes[1];
  const int NT = (N + 15) / 16;
  const int NBINS = (N + 1023) / 1024;

  char* wsp = (char*)d_ws;
  float* hf = (float*)wsp;                      wsp += (size_t)N * 64 * 4;  // fp32 h1
  unsigned short* frags = (unsigned short*)wsp; wsp += 6 * 12288 * 2;
  unsigned* offs = (unsigned*)wsp;   wsp += ((size_t)N + 4) * 4;
  unsigned* cursor = (unsigned*)wsp; wsp += (size_t)N * 4;
  unsigned* rcnt = (unsigned*)wsp;   wsp += (size_t)N * 4;
  uint2* epack = (uint2*)wsp;        wsp += (size_t)E * 8;
  unsigned* bsums = (unsigned*)wsp;  wsp += 128 * 4;
  float* stats = (float*)wsp;        wsp += 128 * 4;

  uint2* binbuf = (uint2*)hf;  // aliases hf: dead until layer_kernel<0> writes it
  unsigned* bincur = cursor;   // reuse counter buffer (dead after scan)

  const unsigned short* frag_t = frags;
  const unsigned short* frag_i = frags + 2 * 12288;
  const unsigned short* frag_h = frags + 4 * 12288;

  const int M = (N + 1023) / 1024;

  hipMemsetAsync(cursor, 0, (size_t)N * 4, stream);
  hipMemsetAsync(stats, 0, 128 * 4, stream);

  wprep_kernel<<<18, 256, 0, stream>>>(W, w_ih, w_hh, frags);

  // CSR over dst (graph is layer-invariant): count -> scan -> (dst,rel) sort
  count_kernel<<<(E / 4 + 255) / 256, 256, 0, stream>>>(dst, cursor, E);
  scan_k1<<<M, 1024, 0, stream>>>(cursor, offs, bsums, N);
  scan_k2<<<1, 128, 0, stream>>>(bsums, offs, M, N);
  scan_k3<<<(N + 255) / 256, 256, 0, stream>>>(offs, bsums, N);
  bin_init_kernel<<<1, 128, 0, stream>>>(offs, bincur, NBINS);
  bin_scatter_kernel<<<(E + SCHUNK - 1) / SCHUNK, 256, 0, stream>>>(
      src, dst, rel, norm, bincur, binbuf, E);
  bin_sort_kernel<<<NBINS, 1024, 0, stream>>>(binbuf, offs, epack, rcnt, N);

  // layer 0: gather from input h; GRU (hstate=0) -> fp32 h1
  layer_kernel<0><<<NT, 256, 0, stream>>>(h, offs, rcnt, epack, frag_t,
                                          frag_i, frag_h, b_ih, b_hh, hf, N);
  // layer 1: gather from h1; GRU (h-path from h1) -> fp32 out
  layer_kernel<1><<<NT, 256, 0, stream>>>(hf, offs, rcnt, epack, frag_t,
                                          frag_i, frag_h, b_ih, b_hh, out, N);

  bn_stats_kernel<<<256, 256, 0, stream>>>(out, stats, N);
  int total = N * 64;
  bn_apply_kernel<<<(total + 255) / 256, 256, 0, stream>>>(out, stats, gamma,
                                                           beta, N, total);
}

// Round 21
// 297.593 us; speedup vs baseline: 1.5908x; 1.0204x over previous
//
#include <hip/hip_runtime.h>

typedef __bf16 bf16x8 __attribute__((ext_vector_type(8)));
typedef float f32x4 __attribute__((ext_vector_type(4)));
typedef short short8 __attribute__((ext_vector_type(8)));

#define MFMA16(a, b, c) __builtin_amdgcn_mfma_f32_16x16x32_bf16(a, b, c, 0, 0, 0)

__device__ inline unsigned short bf16_rne(float x) {
  unsigned u = __builtin_bit_cast(unsigned, x);
  return (unsigned short)((u + 0x7FFFu + ((u >> 16) & 1u)) >> 16);
}
__device__ inline float bf16_tof(unsigned short s) {
  unsigned u = ((unsigned)s) << 16;
  return __builtin_bit_cast(float, u);
}
__device__ inline void split2(float x, unsigned short* hi, unsigned short* lo) {
  unsigned short h = bf16_rne(x);
  *hi = h;
  *lo = bf16_rne(x - bf16_tof(h));
}
__device__ inline float fast_rcp(float x) { return __builtin_amdgcn_rcpf(x); }

// ---------------- weight frag prep (+ cursor zeroing, folded memset) ----------------
// set0 (Wcat, K=192): ((tci*6+ks)*64+lane)*8+j, hi frags[0], lo frags[12288].
// set1 (w_ih) / set2 (w_hh): 12 col-tiles x 2 k-chunks at (2+2*set)*12288.

__global__ __launch_bounds__(256) void wprep_kernel(
    const float* __restrict__ W, const float* __restrict__ w_ih,
    const float* __restrict__ w_hh, unsigned short* __restrict__ frags,
    unsigned* __restrict__ cursor, int N) {
  int idx = blockIdx.x * 256 + threadIdx.x;
  // folded: zero the per-node counter buffer (grid-stride)
  for (int i = idx; i < N; i += gridDim.x * 256) cursor[i] = 0u;
  if (idx < 1536) {
    int lane = idx & 63;
    int ks = (idx >> 6) % 6;
    int tci = idx / (6 * 64);
    int c = tci * 16 + (lane & 15);
    size_t dbase = ((size_t)(tci * 6 + ks) * 64 + lane) * 8;
#pragma unroll
    for (int j = 0; j < 8; ++j) {
      int k = ks * 32 + ((lane >> 4) << 3) + j;  // 0..191
      int r = k >> 6, d = k & 63;
      float v = W[(r << 12) + (d << 6) + c];
      unsigned short h, l;
      split2(v, &h, &l);
      frags[dbase + j] = h;
      frags[12288 + dbase + j] = l;
    }
  } else if (idx < 1536 + 2 * 1536) {
    int i2 = idx - 1536;
    int set = i2 / 1536;
    int i3 = i2 % 1536;
    int lane = i3 & 63;
    int ks = (i3 >> 6) & 1;
    int tci = (i3 >> 7) % 12;
    int c = tci * 16 + (lane & 15);
    unsigned short* hi = frags + (size_t)(2 + 2 * set) * 12288;
    unsigned short* lo = hi + 12288;
    size_t dbase = ((size_t)(tci * 2 + ks) * 64 + lane) * 8;
    const float* wsrc = set ? w_hh : w_ih;
#pragma unroll
    for (int j = 0; j < 8; ++j) {
      int k = ks * 32 + ((lane >> 4) << 3) + j;
      float v = wsrc[(c << 6) + k];
      unsigned short h, l;
      split2(v, &h, &l);
      hi[dbase + j] = h;
      lo[dbase + j] = l;
    }
  }
}

// ---------------- CSR build ----------------

__global__ __launch_bounds__(256) void count_kernel(
    const int* __restrict__ dst, unsigned* __restrict__ counts, int E) {
  int base = (blockIdx.x * 256 + threadIdx.x) * 4;
  if (base + 4 <= E) {
    int4 d = *(const int4*)(dst + base);
    atomicAdd(&counts[d.x], 1u);
    atomicAdd(&counts[d.y], 1u);
    atomicAdd(&counts[d.z], 1u);
    atomicAdd(&counts[d.w], 1u);
  } else {
    for (int k = base; k < E; ++k) atomicAdd(&counts[dst[k]], 1u);
  }
}

__global__ __launch_bounds__(1024) void scan_k1(
    const unsigned* __restrict__ counts, unsigned* __restrict__ offs,
    unsigned* __restrict__ bsums, int N) {
  __shared__ unsigned sm[1024];
  int tid = threadIdx.x;
  int i = blockIdx.x * 1024 + tid;
  unsigned v = (i < N) ? counts[i] : 0u;
  sm[tid] = v;
  __syncthreads();
  for (int ofs = 1; ofs < 1024; ofs <<= 1) {
    unsigned add = (tid >= ofs) ? sm[tid - ofs] : 0u;
    __syncthreads();
    sm[tid] += add;
    __syncthreads();
  }
  if (i < N) offs[i] = sm[tid] - v;
  if (tid == 0) bsums[blockIdx.x] = sm[1023];
}

// block-offset scan; also zeroes BN stats (folded memset)
__global__ __launch_bounds__(128) void scan_k2(
    unsigned* __restrict__ bsums, unsigned* __restrict__ offs,
    float* __restrict__ stats, int M, int N) {
  __shared__ unsigned sm[128];
  int tid = threadIdx.x;
  stats[tid] = 0.f;  // stats has 128 entries
  unsigned v = (tid < M) ? bsums[tid] : 0u;
  sm[tid] = v;
  __syncthreads();
  for (int ofs = 1; ofs < 128; ofs <<= 1) {
    unsigned add = (tid >= ofs) ? sm[tid - ofs] : 0u;
    __syncthreads();
    sm[tid] += add;
    __syncthreads();
  }
  if (tid < M) bsums[tid] = sm[tid] - v;
  if (tid == 127) offs[N] = sm[127];
}

// finalize offs; also initialize per-bin cursors (folded bin_init)
__global__ __launch_bounds__(256) void scan_k3(
    unsigned* __restrict__ offs, const unsigned* __restrict__ bsums,
    unsigned* __restrict__ bincur, int N) {
  int i = blockIdx.x * 256 + threadIdx.x;
  if (i < N) {
    unsigned o = offs[i] + bsums[i >> 10];
    offs[i] = o;
    if ((i & 1023) == 0) bincur[i >> 10] = o;
  }
}

// pass 1: block-aggregated scatter into dst-bins.
#define SCHUNK 2048
__global__ __launch_bounds__(256) void bin_scatter_kernel(
    const int* __restrict__ src, const int* __restrict__ dst,
    const int* __restrict__ rel, const float* __restrict__ norm,
    unsigned* __restrict__ bincur, uint2* __restrict__ binbuf, int E) {
  __shared__ unsigned cnt[128];
  __shared__ unsigned base[128];
  int tid = threadIdx.x;
  int start = blockIdx.x * SCHUNK;
  if (tid < 128) cnt[tid] = 0u;
  __syncthreads();
  unsigned mybin[8];
  uint2 myrec[8];
#pragma unroll
  for (int i = 0; i < 8; ++i) {
    int e = start + i * 256 + tid;
    if (e < E) {
      int d = dst[e];
      mybin[i] = (unsigned)d >> 10;
      myrec[i].x = (unsigned)src[e] | ((unsigned)rel[e] << 17) |
                   ((unsigned)(d & 1023) << 19);
      myrec[i].y = __builtin_bit_cast(unsigned, norm[e]);
      atomicAdd(&cnt[mybin[i]], 1u);
    } else {
      mybin[i] = 0xFFFFFFFFu;
    }
  }
  __syncthreads();
  if (tid < 128) {
    unsigned c = cnt[tid];
    base[tid] = c ? atomicAdd(&bincur[tid], c) : 0u;
    cnt[tid] = 0u;
  }
  __syncthreads();
#pragma unroll
  for (int i = 0; i < 8; ++i) {
    if (mybin[i] != 0xFFFFFFFFu) {
      unsigned r = atomicAdd(&cnt[mybin[i]], 1u);
      binbuf[base[mybin[i]] + r] = myrec[i];
    }
  }
}

// pass 2: per-bin counting sort by (dst, rel); emits per-node run lengths rcnt.
__global__ __launch_bounds__(1024) void bin_sort_kernel(
    const uint2* __restrict__ binbuf, const unsigned* __restrict__ offs,
    uint2* __restrict__ epack, unsigned* __restrict__ rcnt, int N) {
  __shared__ unsigned cnt[3 * 1024];  // per (rel, dlo) counts -> cursors
  __shared__ unsigned offl[1024];
  int bin = blockIdx.x;
  int base = bin << 10;
  int tid = threadIdx.x;
  int hi = base + 1024;
  if (hi > N) hi = N;
  if (base + tid < N) offl[tid] = offs[base + tid];
  cnt[tid] = 0u;
  cnt[1024 + tid] = 0u;
  cnt[2048 + tid] = 0u;
  __syncthreads();
  unsigned start = offs[base];
  unsigned end = offs[hi];
  for (unsigned j = start + tid; j < end; j += 1024) {
    uint2 rec = binbuf[j];
    unsigned dlo = rec.x >> 19;
    unsigned r = (rec.x >> 17) & 3;
    atomicAdd(&cnt[r * 1024 + dlo], 1u);
  }
  __syncthreads();
  unsigned c0 = cnt[tid], c1 = cnt[1024 + tid];
  int n = base + tid;
  if (n < N) rcnt[n] = c0 | (c1 << 16);
  unsigned o = (n < N) ? offl[tid] : 0u;
  cnt[tid] = o;
  cnt[1024 + tid] = o + c0;
  cnt[2048 + tid] = o + c0 + c1;
  __syncthreads();
  for (unsigned j = start + tid; j < end; j += 1024) {
    uint2 rec = binbuf[j];
    unsigned dlo = rec.x >> 19;
    unsigned r = (rec.x >> 17) & 3;
    unsigned p = atomicAdd(&cnt[r * 1024 + dlo], 1u);
    epack[p] = rec;
  }
}

// ---------------- fused layer: gather + Wcat-GEMM + GRU ----------------
// Per block: 16 nodes. Phase 1 gathers z[3][64] (rel-sorted runs, fp32),
// 4-deep unrolled inside the PROVEN lambda shape. (Byte-identical to R20.)
// Phase 2: K=192 split-bf16 MFMA -> swh tile (LDS). Phase 3: GRU MFMAs +
// register gates; LAYER=0 writes fp32 h1, LAYER=1 reads hf rows for the
// h-path (split in-kernel) and hp (exact fp32), writes fp32 out.

template <int LAYER>
__global__ __launch_bounds__(256) void layer_kernel(
    const float* __restrict__ xf, const unsigned* __restrict__ offs,
    const unsigned* __restrict__ rcnt, const uint2* __restrict__ epack,
    const unsigned short* __restrict__ wft,
    const unsigned short* __restrict__ wfi, const unsigned short* __restrict__ wfh,
    const float* __restrict__ b_ih, const float* __restrict__ b_hh,
    float* __restrict__ outf, int N) {
  __shared__ float zld[16][197];
  __shared__ float swht[16][69];
  int tid = threadIdx.x;
  int n0 = blockIdx.x << 4;

  // ---- phase 1: gather (one 16-lane group per node; rel runs) ----
  {
    int g = tid >> 4, l16 = tid & 15;
    int n = n0 + g;
    int c4 = l16 << 2;
    float z0[4] = {}, z1[4] = {}, z2[4] = {};
    if (n < N) {
      unsigned a = offs[n], b = offs[n + 1];
      unsigned rc = rcnt[n];
      unsigned b1 = a + (rc & 0xFFFFu), b2 = b1 + (rc >> 16);
      auto run = [&](unsigned s, unsigned e, float* z) {
        unsigned j = s;
        for (; j + 4 <= e; j += 4) {
          uint2 e0 = epack[j], e1 = epack[j + 1];
          uint2 e2 = epack[j + 2], e3 = epack[j + 3];
          float4 v0 = *(const float4*)(xf + (((size_t)(e0.x & 0x1FFFFu)) << 6) + c4);
          float4 v1 = *(const float4*)(xf + (((size_t)(e1.x & 0x1FFFFu)) << 6) + c4);
          float4 v2 = *(const float4*)(xf + (((size_t)(e2.x & 0x1FFFFu)) << 6) + c4);
          float4 v3 = *(const float4*)(xf + (((size_t)(e3.x & 0x1FFFFu)) << 6) + c4);
          float nv0 = __builtin_bit_cast(float, e0.y);
          float nv1 = __builtin_bit_cast(float, e1.y);
          float nv2 = __builtin_bit_cast(float, e2.y);
          float nv3 = __builtin_bit_cast(float, e3.y);
          z[0] = fmaf(nv0, v0.x, fmaf(nv1, v1.x, fmaf(nv2, v2.x, fmaf(nv3, v3.x, z[0]))));
          z[1] = fmaf(nv0, v0.y, fmaf(nv1, v1.y, fmaf(nv2, v2.y, fmaf(nv3, v3.y, z[1]))));
          z[2] = fmaf(nv0, v0.z, fmaf(nv1, v1.z, fmaf(nv2, v2.z, fmaf(nv3, v3.z, z[2]))));
          z[3] = fmaf(nv0, v0.w, fmaf(nv1, v1.w, fmaf(nv2, v2.w, fmaf(nv3, v3.w, z[3]))));
        }
        for (; j + 2 <= e; j += 2) {
          uint2 e0 = epack[j], e1 = epack[j + 1];
          float4 v0 = *(const float4*)(xf + (((size_t)(e0.x & 0x1FFFFu)) << 6) + c4);
          float4 v1 = *(const float4*)(xf + (((size_t)(e1.x & 0x1FFFFu)) << 6) + c4);
          float nv0 = __builtin_bit_cast(float, e0.y);
          float nv1 = __builtin_bit_cast(float, e1.y);
          z[0] = fmaf(nv0, v0.x, fmaf(nv1, v1.x, z[0]));
          z[1] = fmaf(nv0, v0.y, fmaf(nv1, v1.y, z[1]));
          z[2] = fmaf(nv0, v0.z, fmaf(nv1, v1.z, z[2]));
          z[3] = fmaf(nv0, v0.w, fmaf(nv1, v1.w, z[3]));
        }
        if (j < e) {
          uint2 e0 = epack[j];
          float4 v0 = *(const float4*)(xf + (((size_t)(e0.x & 0x1FFFFu)) << 6) + c4);
          float nv0 = __builtin_bit_cast(float, e0.y);
          z[0] = fmaf(nv0, v0.x, z[0]);
          z[1] = fmaf(nv0, v0.y, z[1]);
          z[2] = fmaf(nv0, v0.z, z[2]);
          z[3] = fmaf(nv0, v0.w, z[3]);
        }
      };
      run(a, b1, z0);
      run(b1, b2, z1);
      run(b2, b, z2);
    }
#pragma unroll
    for (int i = 0; i < 4; ++i) {
      zld[g][c4 + i] = z0[i];
      zld[g][64 + c4 + i] = z1[i];
      zld[g][128 + c4 + i] = z2[i];
    }
  }
  __syncthreads();

  // ---- phase 2: z @ Wcat (K=192) -> swht ----
  int lane = tid & 63, w = tid >> 6;
  int r15 = lane & 15, kq = lane >> 4;
  {
    const short8* fh = (const short8*)wft;
    const short8* fl = (const short8*)(wft + 12288);
    f32x4 acc = {0.f, 0.f, 0.f, 0.f};
#pragma unroll
    for (int ks = 0; ks < 6; ++ks) {
      const float* zr = &zld[r15][ks * 32 + (kq << 3)];
      short8 th, tl;
#pragma unroll
      for (int jj = 0; jj < 8; ++jj) {
        unsigned short h_, l_;
        split2(zr[jj], &h_, &l_);
        th[jj] = (short)h_;
        tl[jj] = (short)l_;
      }
      bf16x8 ahi = __builtin_bit_cast(bf16x8, th);
      bf16x8 alo = __builtin_bit_cast(bf16x8, tl);
      bf16x8 bhi = __builtin_bit_cast(bf16x8, fh[(w * 6 + ks) * 64 + lane]);
      bf16x8 blo = __builtin_bit_cast(bf16x8, fl[(w * 6 + ks) * 64 + lane]);
      acc = MFMA16(ahi, bhi, acc);
      acc = MFMA16(ahi, blo, acc);
      acc = MFMA16(alo, bhi, acc);
    }
    int c = (w << 4) + r15;
#pragma unroll
    for (int reg = 0; reg < 4; ++reg) swht[(kq << 2) + reg][c] = acc[reg];
  }
  __syncthreads();

  // ---- phase 3: GRU ----
  {
    int c = (w << 4) + r15;
    int row = n0 + r15;
    if (row >= N) row = N - 1;

    bf16x8 axh[2], axl[2], ahh2[2], ahl2[2];
#pragma unroll
    for (int ks = 0; ks < 2; ++ks) {
      const float* sr = &swht[r15][(ks << 5) + (kq << 3)];
      short8 th, tl;
#pragma unroll
      for (int jj = 0; jj < 8; ++jj) {
        unsigned short h_, l_;
        split2(sr[jj], &h_, &l_);
        th[jj] = (short)h_;
        tl[jj] = (short)l_;
      }
      axh[ks] = __builtin_bit_cast(bf16x8, th);
      axl[ks] = __builtin_bit_cast(bf16x8, tl);
    }
    if (LAYER) {
#pragma unroll
      for (int ks = 0; ks < 2; ++ks) {
        const float* hr = xf + (((size_t)row) << 6) + ks * 32 + (kq << 3);
        float4 h0 = *(const float4*)hr;
        float4 h1v = *(const float4*)(hr + 4);
        float hv[8] = {h0.x, h0.y, h0.z, h0.w, h1v.x, h1v.y, h1v.z, h1v.w};
        short8 th, tl;
#pragma unroll
        for (int jj = 0; jj < 8; ++jj) {
          unsigned short h_, l_;
          split2(hv[jj], &h_, &l_);
          th[jj] = (short)h_;
          tl[jj] = (short)l_;
        }
        ahh2[ks] = __builtin_bit_cast(bf16x8, th);
        ahl2[ks] = __builtin_bit_cast(bf16x8, tl);
      }
    }

    const short8* fih = (const short8*)wfi;
    const short8* fil = (const short8*)(wfi + 12288);
    const short8* fhh = (const short8*)wfh;
    const short8* fhl = (const short8*)(wfh + 12288);
    f32x4 accx[3], acch[3];
#pragma unroll
    for (int g = 0; g < 3; ++g) {
      accx[g] = (f32x4){0.f, 0.f, 0.f, 0.f};
      acch[g] = (f32x4){0.f, 0.f, 0.f, 0.f};
#pragma unroll
      for (int ks = 0; ks < 2; ++ks) {
        int tci = (g << 2) + w;
        bf16x8 bih = __builtin_bit_cast(bf16x8, fih[(tci * 2 + ks) * 64 + lane]);
        bf16x8 bil = __builtin_bit_cast(bf16x8, fil[(tci * 2 + ks) * 64 + lane]);
        accx[g] = MFMA16(axh[ks], bih, accx[g]);
        accx[g] = MFMA16(axh[ks], bil, accx[g]);
        accx[g] = MFMA16(axl[ks], bih, accx[g]);
        if (LAYER) {
          bf16x8 bhh = __builtin_bit_cast(bf16x8, fhh[(tci * 2 + ks) * 64 + lane]);
          bf16x8 bhl = __builtin_bit_cast(bf16x8, fhl[(tci * 2 + ks) * 64 + lane]);
          acch[g] = MFMA16(ahh2[ks], bhh, acch[g]);
          acch[g] = MFMA16(ahh2[ks], bhl, acch[g]);
          acch[g] = MFMA16(ahl2[ks], bhh, acch[g]);
        }
      }
    }

    float bi0 = b_ih[c], bi1 = b_ih[64 + c], bi2 = b_ih[128 + c];
    float bh0 = b_hh[c], bh1 = b_hh[64 + c], bh2 = b_hh[128 + c];
#pragma unroll
    for (int reg = 0; reg < 4; ++reg) {
      int n = n0 + (kq << 2) + reg;
      if (n >= N) break;
      size_t idx = (((size_t)n) << 6) + c;
      float hp = LAYER ? xf[idx] : 0.f;
      float gir = accx[0][reg] + bi0;
      float giz = accx[1][reg] + bi1;
      float gin = accx[2][reg] + bi2;
      float ghr = (LAYER ? acch[0][reg] : 0.f) + bh0;
      float ghz = (LAYER ? acch[1][reg] : 0.f) + bh1;
      float ghn = (LAYER ? acch[2][reg] : 0.f) + bh2;
      float r = fast_rcp(1.f + __expf(-(gir + ghr)));
      float z = fast_rcp(1.f + __expf(-(giz + ghz)));
      float nn = 1.f - 2.f * fast_rcp(1.f + __expf(2.f * (gin + r * ghn)));
      outf[idx] = (1.f - z) * nn + z * hp;
    }
  }
}

// ---------------- batchnorm ----------------

__global__ __launch_bounds__(256) void bn_stats_kernel(
    const float* __restrict__ h, float* __restrict__ stats, int N) {
  int tid = threadIdx.x;
  int c = tid & 63;
  float s = 0.f, ss = 0.f;
  for (int n = blockIdx.x * 4 + (tid >> 6); n < N; n += gridDim.x * 4) {
    float v = h[(size_t)n * 64 + c];
    s += v;
    ss += v * v;
  }
  __shared__ float sm[2][256];
  sm[0][tid] = s;
  sm[1][tid] = ss;
  __syncthreads();
  if (tid < 64) {
    s = sm[0][tid] + sm[0][tid + 64] + sm[0][tid + 128] + sm[0][tid + 192];
    ss = sm[1][tid] + sm[1][tid + 64] + sm[1][tid + 128] + sm[1][tid + 192];
    atomicAdd(&stats[tid], s);
    atomicAdd(&stats[64 + tid], ss);
  }
}

__global__ __launch_bounds__(256) void bn_apply_kernel(
    float* out, const float* __restrict__ stats,
    const float* __restrict__ gamma, const float* __restrict__ beta,
    int N, int total) {
  int idx = blockIdx.x * 256 + threadIdx.x;
  if (idx >= total) return;
  int c = idx & 63;
  float invN = 1.f / (float)N;
  float mean = stats[c] * invN;
  float var = stats[64 + c] * invN - mean * mean;
  float sc = rsqrtf(var + 1e-5f) * gamma[c];
  float sh = beta[c] - mean * sc;
  out[idx] = out[idx] * sc + sh;
}

// ---------------- launch ----------------

extern "C" void kernel_launch(void* const* d_in, const int* in_sizes, int n_in,
                              void* d_out, int out_size, void* d_ws, size_t ws_size,
                              hipStream_t stream) {
  const float* h     = (const float*)d_in[0];
  const float* norm  = (const float*)d_in[1];
  const float* W     = (const float*)d_in[2];
  const float* w_ih  = (const float*)d_in[3];
  const float* w_hh  = (const float*)d_in[4];
  const float* b_ih  = (const float*)d_in[5];
  const float* b_hh  = (const float*)d_in[6];
  const float* gamma = (const float*)d_in[7];
  const float* beta  = (const float*)d_in[8];
  const int* src     = (const int*)d_in[9];
  const int* dst     = (const int*)d_in[10];
  const int* rel     = (const int*)d_in[11];
  float* out = (float*)d_out;

  const int N = in_sizes[0] / 64;
  const int E = in_sizes[1];
  const int NT = (N + 15) / 16;
  const int NBINS = (N + 1023) / 1024;

  char* wsp = (char*)d_ws;
  float* hf = (float*)wsp;                      wsp += (size_t)N * 64 * 4;  // fp32 h1
  unsigned short* frags = (unsigned short*)wsp; wsp += 6 * 12288 * 2;
  unsigned* offs = (unsigned*)wsp;   wsp += ((size_t)N + 4) * 4;
  unsigned* cursor = (unsigned*)wsp; wsp += (size_t)N * 4;
  unsigned* rcnt = (unsigned*)wsp;   wsp += (size_t)N * 4;
  uint2* epack = (uint2*)wsp;        wsp += (size_t)E * 8;
  unsigned* bsums = (unsigned*)wsp;  wsp += 128 * 4;
  float* stats = (float*)wsp;        wsp += 128 * 4;

  uint2* binbuf = (uint2*)hf;  // aliases hf: dead until layer_kernel<0> writes it
  unsigned* bincur = cursor;   // reuse counter buffer (dead after scan)

  const unsigned short* frag_t = frags;
  const unsigned short* frag_i = frags + 2 * 12288;
  const unsigned short* frag_h = frags + 4 * 12288;

  const int M = (N + 1023) / 1024;

  // wprep also zeroes cursor (folded memset); 18 blocks grid-stride covers N
  wprep_kernel<<<64, 256, 0, stream>>>(W, w_ih, w_hh, frags, cursor, N);

  // CSR over dst (graph is layer-invariant): count -> scan -> (dst,rel) sort
  count_kernel<<<(E / 4 + 255) / 256, 256, 0, stream>>>(dst, cursor, E);
  scan_k1<<<M, 1024, 0, stream>>>(cursor, offs, bsums, N);
  scan_k2<<<1, 128, 0, stream>>>(bsums, offs, stats, M, N);  // + stats zeroing
  scan_k3<<<(N + 255) / 256, 256, 0, stream>>>(offs, bsums, bincur, N);  // + bin_init
  bin_scatter_kernel<<<(E + SCHUNK - 1) / SCHUNK, 256, 0, stream>>>(
      src, dst, rel, norm, bincur, binbuf, E);
  bin_sort_kernel<<<NBINS, 1024, 0, stream>>>(binbuf, offs, epack, rcnt, N);

  // layer 0: gather from input h; GRU (hstate=0) -> fp32 h1
  layer_kernel<0><<<NT, 256, 0, stream>>>(h, offs, rcnt, epack, frag_t,
                                          frag_i, frag_h, b_ih, b_hh, hf, N);
  // layer 1: gather from h1; GRU (h-path from h1) -> fp32 out
  layer_kernel<1><<<NT, 256, 0, stream>>>(hf, offs, rcnt, epack, frag_t,
                                          frag_i, frag_h, b_ih, b_hh, out, N);

  bn_stats_kernel<<<256, 256, 0, stream>>>(out, stats, N);
  int total = N * 64;
  bn_apply_kernel<<<(total + 255) / 256, 256, 0, stream>>>(out, stats, gamma,
                                                           beta, N, total);
}

// Round 22
// 296.210 us; speedup vs baseline: 1.5982x; 1.0047x over previous
//
#include <hip/hip_runtime.h>

typedef __bf16 bf16x8 __attribute__((ext_vector_type(8)));
typedef float f32x4 __attribute__((ext_vector_type(4)));
typedef short short8 __attribute__((ext_vector_type(8)));

#define MFMA16(a, b, c) __builtin_amdgcn_mfma_f32_16x16x32_bf16(a, b, c, 0, 0, 0)

__device__ inline unsigned short bf16_rne(float x) {
  unsigned u = __builtin_bit_cast(unsigned, x);
  return (unsigned short)((u + 0x7FFFu + ((u >> 16) & 1u)) >> 16);
}
__device__ inline float bf16_tof(unsigned short s) {
  unsigned u = ((unsigned)s) << 16;
  return __builtin_bit_cast(float, u);
}
__device__ inline void split2(float x, unsigned short* hi, unsigned short* lo) {
  unsigned short h = bf16_rne(x);
  *hi = h;
  *lo = bf16_rne(x - bf16_tof(h));
}
__device__ inline float fast_rcp(float x) { return __builtin_amdgcn_rcpf(x); }

// ---------------- weight frag prep (+ cursor zeroing, folded memset) ----------------
// set0 (Wcat, K=192): ((tci*6+ks)*64+lane)*8+j, hi frags[0], lo frags[12288].
// set1 (w_ih) / set2 (w_hh): 12 col-tiles x 2 k-chunks at (2+2*set)*12288.

__global__ __launch_bounds__(256) void wprep_kernel(
    const float* __restrict__ W, const float* __restrict__ w_ih,
    const float* __restrict__ w_hh, unsigned short* __restrict__ frags,
    unsigned* __restrict__ cursor, int N) {
  int idx = blockIdx.x * 256 + threadIdx.x;
  // folded: zero the per-node counter buffer (grid-stride)
  for (int i = idx; i < N; i += gridDim.x * 256) cursor[i] = 0u;
  if (idx < 1536) {
    int lane = idx & 63;
    int ks = (idx >> 6) % 6;
    int tci = idx / (6 * 64);
    int c = tci * 16 + (lane & 15);
    size_t dbase = ((size_t)(tci * 6 + ks) * 64 + lane) * 8;
#pragma unroll
    for (int j = 0; j < 8; ++j) {
      int k = ks * 32 + ((lane >> 4) << 3) + j;  // 0..191
      int r = k >> 6, d = k & 63;
      float v = W[(r << 12) + (d << 6) + c];
      unsigned short h, l;
      split2(v, &h, &l);
      frags[dbase + j] = h;
      frags[12288 + dbase + j] = l;
    }
  } else if (idx < 1536 + 2 * 1536) {
    int i2 = idx - 1536;
    int set = i2 / 1536;
    int i3 = i2 % 1536;
    int lane = i3 & 63;
    int ks = (i3 >> 6) & 1;
    int tci = (i3 >> 7) % 12;
    int c = tci * 16 + (lane & 15);
    unsigned short* hi = frags + (size_t)(2 + 2 * set) * 12288;
    unsigned short* lo = hi + 12288;
    size_t dbase = ((size_t)(tci * 2 + ks) * 64 + lane) * 8;
    const float* wsrc = set ? w_hh : w_ih;
#pragma unroll
    for (int j = 0; j < 8; ++j) {
      int k = ks * 32 + ((lane >> 4) << 3) + j;
      float v = wsrc[(c << 6) + k];
      unsigned short h, l;
      split2(v, &h, &l);
      hi[dbase + j] = h;
      lo[dbase + j] = l;
    }
  }
}

// ---------------- CSR build ----------------

__global__ __launch_bounds__(256) void count_kernel(
    const int* __restrict__ dst, unsigned* __restrict__ counts, int E) {
  int base = (blockIdx.x * 256 + threadIdx.x) * 4;
  if (base + 4 <= E) {
    int4 d = *(const int4*)(dst + base);
    atomicAdd(&counts[d.x], 1u);
    atomicAdd(&counts[d.y], 1u);
    atomicAdd(&counts[d.z], 1u);
    atomicAdd(&counts[d.w], 1u);
  } else {
    for (int k = base; k < E; ++k) atomicAdd(&counts[dst[k]], 1u);
  }
}

__global__ __launch_bounds__(1024) void scan_k1(
    const unsigned* __restrict__ counts, unsigned* __restrict__ offs,
    unsigned* __restrict__ bsums, int N) {
  __shared__ unsigned sm[1024];
  int tid = threadIdx.x;
  int i = blockIdx.x * 1024 + tid;
  unsigned v = (i < N) ? counts[i] : 0u;
  sm[tid] = v;
  __syncthreads();
  for (int ofs = 1; ofs < 1024; ofs <<= 1) {
    unsigned add = (tid >= ofs) ? sm[tid - ofs] : 0u;
    __syncthreads();
    sm[tid] += add;
    __syncthreads();
  }
  if (i < N) offs[i] = sm[tid] - v;
  if (tid == 0) bsums[blockIdx.x] = sm[1023];
}

// finalize offs (each block redundantly scans the <=128 block sums in LDS);
// also initializes per-bin cursors (folded bin_init), writes offs[N], and
// zeroes BN stats (folded scan_k2 + memset). bsums stays raw in global.
__global__ __launch_bounds__(256) void scan_k3(
    unsigned* __restrict__ offs, const unsigned* __restrict__ bsums,
    unsigned* __restrict__ bincur, float* __restrict__ stats, int M, int N) {
  __shared__ unsigned sm[128];
  int tid = threadIdx.x;
  if (tid < 128) sm[tid] = (tid < M) ? bsums[tid] : 0u;
  __syncthreads();
  for (int ofs = 1; ofs < 128; ofs <<= 1) {
    unsigned add = 0u;
    if (tid < 128 && tid >= ofs) add = sm[tid - ofs];
    __syncthreads();
    if (tid < 128) sm[tid] += add;
    __syncthreads();
  }
  int i = blockIdx.x * 256 + tid;
  if (i < N) {
    int blk = i >> 10;
    unsigned excl = sm[blk] - bsums[blk];  // exclusive prefix
    unsigned o = offs[i] + excl;
    offs[i] = o;
    if ((i & 1023) == 0) bincur[blk] = o;
  }
  if (blockIdx.x == 0) {
    if (tid == 0) offs[N] = sm[127];
    if (tid < 128) stats[tid] = 0.f;
  }
}

// pass 1: block-aggregated scatter into dst-bins.
#define SCHUNK 2048
__global__ __launch_bounds__(256) void bin_scatter_kernel(
    const int* __restrict__ src, const int* __restrict__ dst,
    const int* __restrict__ rel, const float* __restrict__ norm,
    unsigned* __restrict__ bincur, uint2* __restrict__ binbuf, int E) {
  __shared__ unsigned cnt[128];
  __shared__ unsigned base[128];
  int tid = threadIdx.x;
  int start = blockIdx.x * SCHUNK;
  if (tid < 128) cnt[tid] = 0u;
  __syncthreads();
  unsigned mybin[8];
  uint2 myrec[8];
#pragma unroll
  for (int i = 0; i < 8; ++i) {
    int e = start + i * 256 + tid;
    if (e < E) {
      int d = dst[e];
      mybin[i] = (unsigned)d >> 10;
      myrec[i].x = (unsigned)src[e] | ((unsigned)rel[e] << 17) |
                   ((unsigned)(d & 1023) << 19);
      myrec[i].y = __builtin_bit_cast(unsigned, norm[e]);
      atomicAdd(&cnt[mybin[i]], 1u);
    } else {
      mybin[i] = 0xFFFFFFFFu;
    }
  }
  __syncthreads();
  if (tid < 128) {
    unsigned c = cnt[tid];
    base[tid] = c ? atomicAdd(&bincur[tid], c) : 0u;
    cnt[tid] = 0u;
  }
  __syncthreads();
#pragma unroll
  for (int i = 0; i < 8; ++i) {
    if (mybin[i] != 0xFFFFFFFFu) {
      unsigned r = atomicAdd(&cnt[mybin[i]], 1u);
      binbuf[base[mybin[i]] + r] = myrec[i];
    }
  }
}

// pass 2: per-bin counting sort by (dst, rel); emits per-node run lengths rcnt.
__global__ __launch_bounds__(1024) void bin_sort_kernel(
    const uint2* __restrict__ binbuf, const unsigned* __restrict__ offs,
    uint2* __restrict__ epack, unsigned* __restrict__ rcnt, int N) {
  __shared__ unsigned cnt[3 * 1024];  // per (rel, dlo) counts -> cursors
  __shared__ unsigned offl[1024];
  int bin = blockIdx.x;
  int base = bin << 10;
  int tid = threadIdx.x;
  int hi = base + 1024;
  if (hi > N) hi = N;
  if (base + tid < N) offl[tid] = offs[base + tid];
  cnt[tid] = 0u;
  cnt[1024 + tid] = 0u;
  cnt[2048 + tid] = 0u;
  __syncthreads();
  unsigned start = offs[base];
  unsigned end = offs[hi];
  for (unsigned j = start + tid; j < end; j += 1024) {
    uint2 rec = binbuf[j];
    unsigned dlo = rec.x >> 19;
    unsigned r = (rec.x >> 17) & 3;
    atomicAdd(&cnt[r * 1024 + dlo], 1u);
  }
  __syncthreads();
  unsigned c0 = cnt[tid], c1 = cnt[1024 + tid];
  int n = base + tid;
  if (n < N) rcnt[n] = c0 | (c1 << 16);
  unsigned o = (n < N) ? offl[tid] : 0u;
  cnt[tid] = o;
  cnt[1024 + tid] = o + c0;
  cnt[2048 + tid] = o + c0 + c1;
  __syncthreads();
  for (unsigned j = start + tid; j < end; j += 1024) {
    uint2 rec = binbuf[j];
    unsigned dlo = rec.x >> 19;
    unsigned r = (rec.x >> 17) & 3;
    unsigned p = atomicAdd(&cnt[r * 1024 + dlo], 1u);
    epack[p] = rec;
  }
}

// ---------------- fused layer: gather + Wcat-GEMM + GRU ----------------
// Per block: 16 nodes. Phase 1 gathers z[3][64] (rel-sorted runs, fp32),
// 4-deep unrolled inside the PROVEN lambda shape. (Byte-identical to R20/R21.)
// Phase 2: K=192 split-bf16 MFMA -> swh tile (LDS). Phase 3: GRU MFMAs +
// register gates; LAYER=0 writes fp32 h1, LAYER=1 reads hf rows for the
// h-path (split in-kernel) and hp (exact fp32), writes fp32 out.
// NOTE: BN-stats fusion into this kernel is empirically poison (4/4 broken
// variants, R13/14/15/18) — keep bn_stats as a separate kernel.

template <int LAYER>
__global__ __launch_bounds__(256) void layer_kernel(
    const float* __restrict__ xf, const unsigned* __restrict__ offs,
    const unsigned* __restrict__ rcnt, const uint2* __restrict__ epack,
    const unsigned short* __restrict__ wft,
    const unsigned short* __restrict__ wfi, const unsigned short* __restrict__ wfh,
    const float* __restrict__ b_ih, const float* __restrict__ b_hh,
    float* __restrict__ outf, int N) {
  __shared__ float zld[16][197];
  __shared__ float swht[16][69];
  int tid = threadIdx.x;
  int n0 = blockIdx.x << 4;

  // ---- phase 1: gather (one 16-lane group per node; rel runs) ----
  {
    int g = tid >> 4, l16 = tid & 15;
    int n = n0 + g;
    int c4 = l16 << 2;
    float z0[4] = {}, z1[4] = {}, z2[4] = {};
    if (n < N) {
      unsigned a = offs[n], b = offs[n + 1];
      unsigned rc = rcnt[n];
      unsigned b1 = a + (rc & 0xFFFFu), b2 = b1 + (rc >> 16);
      auto run = [&](unsigned s, unsigned e, float* z) {
        unsigned j = s;
        for (; j + 4 <= e; j += 4) {
          uint2 e0 = epack[j], e1 = epack[j + 1];
          uint2 e2 = epack[j + 2], e3 = epack[j + 3];
          float4 v0 = *(const float4*)(xf + (((size_t)(e0.x & 0x1FFFFu)) << 6) + c4);
          float4 v1 = *(const float4*)(xf + (((size_t)(e1.x & 0x1FFFFu)) << 6) + c4);
          float4 v2 = *(const float4*)(xf + (((size_t)(e2.x & 0x1FFFFu)) << 6) + c4);
          float4 v3 = *(const float4*)(xf + (((size_t)(e3.x & 0x1FFFFu)) << 6) + c4);
          float nv0 = __builtin_bit_cast(float, e0.y);
          float nv1 = __builtin_bit_cast(float, e1.y);
          float nv2 = __builtin_bit_cast(float, e2.y);
          float nv3 = __builtin_bit_cast(float, e3.y);
          z[0] = fmaf(nv0, v0.x, fmaf(nv1, v1.x, fmaf(nv2, v2.x, fmaf(nv3, v3.x, z[0]))));
          z[1] = fmaf(nv0, v0.y, fmaf(nv1, v1.y, fmaf(nv2, v2.y, fmaf(nv3, v3.y, z[1]))));
          z[2] = fmaf(nv0, v0.z, fmaf(nv1, v1.z, fmaf(nv2, v2.z, fmaf(nv3, v3.z, z[2]))));
          z[3] = fmaf(nv0, v0.w, fmaf(nv1, v1.w, fmaf(nv2, v2.w, fmaf(nv3, v3.w, z[3]))));
        }
        for (; j + 2 <= e; j += 2) {
          uint2 e0 = epack[j], e1 = epack[j + 1];
          float4 v0 = *(const float4*)(xf + (((size_t)(e0.x & 0x1FFFFu)) << 6) + c4);
          float4 v1 = *(const float4*)(xf + (((size_t)(e1.x & 0x1FFFFu)) << 6) + c4);
          float nv0 = __builtin_bit_cast(float, e0.y);
          float nv1 = __builtin_bit_cast(float, e1.y);
          z[0] = fmaf(nv0, v0.x, fmaf(nv1, v1.x, z[0]));
          z[1] = fmaf(nv0, v0.y, fmaf(nv1, v1.y, z[1]));
          z[2] = fmaf(nv0, v0.z, fmaf(nv1, v1.z, z[2]));
          z[3] = fmaf(nv0, v0.w, fmaf(nv1, v1.w, z[3]));
        }
        if (j < e) {
          uint2 e0 = epack[j];
          float4 v0 = *(const float4*)(xf + (((size_t)(e0.x & 0x1FFFFu)) << 6) + c4);
          float nv0 = __builtin_bit_cast(float, e0.y);
          z[0] = fmaf(nv0, v0.x, z[0]);
          z[1] = fmaf(nv0, v0.y, z[1]);
          z[2] = fmaf(nv0, v0.z, z[2]);
          z[3] = fmaf(nv0, v0.w, z[3]);
        }
      };
      run(a, b1, z0);
      run(b1, b2, z1);
      run(b2, b, z2);
    }
#pragma unroll
    for (int i = 0; i < 4; ++i) {
      zld[g][c4 + i] = z0[i];
      zld[g][64 + c4 + i] = z1[i];
      zld[g][128 + c4 + i] = z2[i];
    }
  }
  __syncthreads();

  // ---- phase 2: z @ Wcat (K=192) -> swht ----
  int lane = tid & 63, w = tid >> 6;
  int r15 = lane & 15, kq = lane >> 4;
  {
    const short8* fh = (const short8*)wft;
    const short8* fl = (const short8*)(wft + 12288);
    f32x4 acc = {0.f, 0.f, 0.f, 0.f};
#pragma unroll
    for (int ks = 0; ks < 6; ++ks) {
      const float* zr = &zld[r15][ks * 32 + (kq << 3)];
      short8 th, tl;
#pragma unroll
      for (int jj = 0; jj < 8; ++jj) {
        unsigned short h_, l_;
        split2(zr[jj], &h_, &l_);
        th[jj] = (short)h_;
        tl[jj] = (short)l_;
      }
      bf16x8 ahi = __builtin_bit_cast(bf16x8, th);
      bf16x8 alo = __builtin_bit_cast(bf16x8, tl);
      bf16x8 bhi = __builtin_bit_cast(bf16x8, fh[(w * 6 + ks) * 64 + lane]);
      bf16x8 blo = __builtin_bit_cast(bf16x8, fl[(w * 6 + ks) * 64 + lane]);
      acc = MFMA16(ahi, bhi, acc);
      acc = MFMA16(ahi, blo, acc);
      acc = MFMA16(alo, bhi, acc);
    }
    int c = (w << 4) + r15;
#pragma unroll
    for (int reg = 0; reg < 4; ++reg) swht[(kq << 2) + reg][c] = acc[reg];
  }
  __syncthreads();

  // ---- phase 3: GRU ----
  {
    int c = (w << 4) + r15;
    int row = n0 + r15;
    if (row >= N) row = N - 1;

    bf16x8 axh[2], axl[2], ahh2[2], ahl2[2];
#pragma unroll
    for (int ks = 0; ks < 2; ++ks) {
      const float* sr = &swht[r15][(ks << 5) + (kq << 3)];
      short8 th, tl;
#pragma unroll
      for (int jj = 0; jj < 8; ++jj) {
        unsigned short h_, l_;
        split2(sr[jj], &h_, &l_);
        th[jj] = (short)h_;
        tl[jj] = (short)l_;
      }
      axh[ks] = __builtin_bit_cast(bf16x8, th);
      axl[ks] = __builtin_bit_cast(bf16x8, tl);
    }
    if (LAYER) {
#pragma unroll
      for (int ks = 0; ks < 2; ++ks) {
        const float* hr = xf + (((size_t)row) << 6) + ks * 32 + (kq << 3);
        float4 h0 = *(const float4*)hr;
        float4 h1v = *(const float4*)(hr + 4);
        float hv[8] = {h0.x, h0.y, h0.z, h0.w, h1v.x, h1v.y, h1v.z, h1v.w};
        short8 th, tl;
#pragma unroll
        for (int jj = 0; jj < 8; ++jj) {
          unsigned short h_, l_;
          split2(hv[jj], &h_, &l_);
          th[jj] = (short)h_;
          tl[jj] = (short)l_;
        }
        ahh2[ks] = __builtin_bit_cast(bf16x8, th);
        ahl2[ks] = __builtin_bit_cast(bf16x8, tl);
      }
    }

    const short8* fih = (const short8*)wfi;
    const short8* fil = (const short8*)(wfi + 12288);
    const short8* fhh = (const short8*)wfh;
    const short8* fhl = (const short8*)(wfh + 12288);
    f32x4 accx[3], acch[3];
#pragma unroll
    for (int g = 0; g < 3; ++g) {
      accx[g] = (f32x4){0.f, 0.f, 0.f, 0.f};
      acch[g] = (f32x4){0.f, 0.f, 0.f, 0.f};
#pragma unroll
      for (int ks = 0; ks < 2; ++ks) {
        int tci = (g << 2) + w;
        bf16x8 bih = __builtin_bit_cast(bf16x8, fih[(tci * 2 + ks) * 64 + lane]);
        bf16x8 bil = __builtin_bit_cast(bf16x8, fil[(tci * 2 + ks) * 64 + lane]);
        accx[g] = MFMA16(axh[ks], bih, accx[g]);
        accx[g] = MFMA16(axh[ks], bil, accx[g]);
        accx[g] = MFMA16(axl[ks], bih, accx[g]);
        if (LAYER) {
          bf16x8 bhh = __builtin_bit_cast(bf16x8, fhh[(tci * 2 + ks) * 64 + lane]);
          bf16x8 bhl = __builtin_bit_cast(bf16x8, fhl[(tci * 2 + ks) * 64 + lane]);
          acch[g] = MFMA16(ahh2[ks], bhh, acch[g]);
          acch[g] = MFMA16(ahh2[ks], bhl, acch[g]);
          acch[g] = MFMA16(ahl2[ks], bhh, acch[g]);
        }
      }
    }

    float bi0 = b_ih[c], bi1 = b_ih[64 + c], bi2 = b_ih[128 + c];
    float bh0 = b_hh[c], bh1 = b_hh[64 + c], bh2 = b_hh[128 + c];
#pragma unroll
    for (int reg = 0; reg < 4; ++reg) {
      int n = n0 + (kq << 2) + reg;
      if (n >= N) break;
      size_t idx = (((size_t)n) << 6) + c;
      float hp = LAYER ? xf[idx] : 0.f;
      float gir = accx[0][reg] + bi0;
      float giz = accx[1][reg] + bi1;
      float gin = accx[2][reg] + bi2;
      float ghr = (LAYER ? acch[0][reg] : 0.f) + bh0;
      float ghz = (LAYER ? acch[1][reg] : 0.f) + bh1;
      float ghn = (LAYER ? acch[2][reg] : 0.f) + bh2;
      float r = fast_rcp(1.f + __expf(-(gir + ghr)));
      float z = fast_rcp(1.f + __expf(-(giz + ghz)));
      float nn = 1.f - 2.f * fast_rcp(1.f + __expf(2.f * (gin + r * ghn)));
      outf[idx] = (1.f - z) * nn + z * hp;
    }
  }
}

// ---------------- batchnorm ----------------

__global__ __launch_bounds__(256) void bn_stats_kernel(
    const float* __restrict__ h, float* __restrict__ stats, int N) {
  int tid = threadIdx.x;
  int c = tid & 63;
  float s = 0.f, ss = 0.f;
  for (int n = blockIdx.x * 4 + (tid >> 6); n < N; n += gridDim.x * 4) {
    float v = h[(size_t)n * 64 + c];
    s += v;
    ss += v * v;
  }
  __shared__ float sm[2][256];
  sm[0][tid] = s;
  sm[1][tid] = ss;
  __syncthreads();
  if (tid < 64) {
    s = sm[0][tid] + sm[0][tid + 64] + sm[0][tid + 128] + sm[0][tid + 192];
    ss = sm[1][tid] + sm[1][tid + 64] + sm[1][tid + 128] + sm[1][tid + 192];
    atomicAdd(&stats[tid], s);
    atomicAdd(&stats[64 + tid], ss);
  }
}

__global__ __launch_bounds__(256) void bn_apply_kernel(
    float* out, const float* __restrict__ stats,
    const float* __restrict__ gamma, const float* __restrict__ beta,
    int N, int total) {
  int idx = blockIdx.x * 256 + threadIdx.x;
  if (idx >= total) return;
  int c = idx & 63;
  float invN = 1.f / (float)N;
  float mean = stats[c] * invN;
  float var = stats[64 + c] * invN - mean * mean;
  float sc = rsqrtf(var + 1e-5f) * gamma[c];
  float sh = beta[c] - mean * sc;
  out[idx] = out[idx] * sc + sh;
}

// ---------------- launch ----------------

extern "C" void kernel_launch(void* const* d_in, const int* in_sizes, int n_in,
                              void* d_out, int out_size, void* d_ws, size_t ws_size,
                              hipStream_t stream) {
  const float* h     = (const float*)d_in[0];
  const float* norm  = (const float*)d_in[1];
  const float* W     = (const float*)d_in[2];
  const float* w_ih  = (const float*)d_in[3];
  const float* w_hh  = (const float*)d_in[4];
  const float* b_ih  = (const float*)d_in[5];
  const float* b_hh  = (const float*)d_in[6];
  const float* gamma = (const float*)d_in[7];
  const float* beta  = (const float*)d_in[8];
  const int* src     = (const int*)d_in[9];
  const int* dst     = (const int*)d_in[10];
  const int* rel     = (const int*)d_in[11];
  float* out = (float*)d_out;

  const int N = in_sizes[0] / 64;
  const int E = in_sizes[1];
  const int NT = (N + 15) / 16;
  const int NBINS = (N + 1023) / 1024;

  char* wsp = (char*)d_ws;
  float* hf = (float*)wsp;                      wsp += (size_t)N * 64 * 4;  // fp32 h1
  unsigned short* frags = (unsigned short*)wsp; wsp += 6 * 12288 * 2;
  unsigned* offs = (unsigned*)wsp;   wsp += ((size_t)N + 4) * 4;
  unsigned* cursor = (unsigned*)wsp; wsp += (size_t)N * 4;
  unsigned* rcnt = (unsigned*)wsp;   wsp += (size_t)N * 4;
  uint2* epack = (uint2*)wsp;        wsp += (size_t)E * 8;
  unsigned* bsums = (unsigned*)wsp;  wsp += 128 * 4;
  float* stats = (float*)wsp;        wsp += 128 * 4;

  uint2* binbuf = (uint2*)hf;  // aliases hf: dead until layer_kernel<0> writes it
  unsigned* bincur = cursor;   // reuse counter buffer (dead after scan)

  const unsigned short* frag_t = frags;
  const unsigned short* frag_i = frags + 2 * 12288;
  const unsigned short* frag_h = frags + 4 * 12288;

  const int M = (N + 1023) / 1024;

  // wprep also zeroes cursor (folded memset)
  wprep_kernel<<<64, 256, 0, stream>>>(W, w_ih, w_hh, frags, cursor, N);

  // CSR over dst (graph is layer-invariant): count -> scan -> (dst,rel) sort
  count_kernel<<<(E / 4 + 255) / 256, 256, 0, stream>>>(dst, cursor, E);
  scan_k1<<<M, 1024, 0, stream>>>(cursor, offs, bsums, N);
  scan_k3<<<(N + 255) / 256, 256, 0, stream>>>(offs, bsums, bincur, stats, M, N);
  bin_scatter_kernel<<<(E + SCHUNK - 1) / SCHUNK, 256, 0, stream>>>(
      src, dst, rel, norm, bincur, binbuf, E);
  bin_sort_kernel<<<NBINS, 1024, 0, stream>>>(binbuf, offs, epack, rcnt, N);

  // layer 0: gather from input h; GRU (hstate=0) -> fp32 h1
  layer_kernel<0><<<NT, 256, 0, stream>>>(h, offs, rcnt, epack, frag_t,
                                          frag_i, frag_h, b_ih, b_hh, hf, N);
  // layer 1: gather from h1; GRU (h-path from h1) -> fp32 out
  layer_kernel<1><<<NT, 256, 0, stream>>>(hf, offs, rcnt, epack, frag_t,
                                          frag_i, frag_h, b_ih, b_hh, out, N);

  bn_stats_kernel<<<256, 256, 0, stream>>>(out, stats, N);
  int total = N * 64;
  bn_apply_kernel<<<(total + 255) / 256, 256, 0, stream>>>(out, stats, gamma,
                                                           beta, N, total);
}

// Round 23
// 265.744 us; speedup vs baseline: 1.7814x; 1.1146x over previous
//
#include <hip/hip_runtime.h>

typedef __bf16 bf16x8 __attribute__((ext_vector_type(8)));
typedef float f32x4 __attribute__((ext_vector_type(4)));
typedef short short8 __attribute__((ext_vector_type(8)));

#define MFMA16(a, b, c) __builtin_amdgcn_mfma_f32_16x16x32_bf16(a, b, c, 0, 0, 0)

__device__ inline unsigned short bf16_rne(float x) {
  unsigned u = __builtin_bit_cast(unsigned, x);
  return (unsigned short)((u + 0x7FFFu + ((u >> 16) & 1u)) >> 16);
}
__device__ inline float bf16_tof(unsigned short s) {
  unsigned u = ((unsigned)s) << 16;
  return __builtin_bit_cast(float, u);
}
__device__ inline void split2(float x, unsigned short* hi, unsigned short* lo) {
  unsigned short h = bf16_rne(x);
  *hi = h;
  *lo = bf16_rne(x - bf16_tof(h));
}
__device__ inline float fast_rcp(float x) { return __builtin_amdgcn_rcpf(x); }

// ---------------- weight frag prep (+ bincnt zeroing) ----------------
// set0 (Wcat, K=192): ((tci*6+ks)*64+lane)*8+j, hi frags[0], lo frags[12288].
// set1 (w_ih) / set2 (w_hh): 12 col-tiles x 2 k-chunks at (2+2*set)*12288.

__global__ __launch_bounds__(256) void wprep_kernel(
    const float* __restrict__ W, const float* __restrict__ w_ih,
    const float* __restrict__ w_hh, unsigned short* __restrict__ frags,
    unsigned* __restrict__ bincnt) {
  int idx = blockIdx.x * 256 + threadIdx.x;
  if (idx < 128) bincnt[idx] = 0u;  // folded memset (histogram bins)
  if (idx < 1536) {
    int lane = idx & 63;
    int ks = (idx >> 6) % 6;
    int tci = idx / (6 * 64);
    int c = tci * 16 + (lane & 15);
    size_t dbase = ((size_t)(tci * 6 + ks) * 64 + lane) * 8;
#pragma unroll
    for (int j = 0; j < 8; ++j) {
      int k = ks * 32 + ((lane >> 4) << 3) + j;  // 0..191
      int r = k >> 6, d = k & 63;
      float v = W[(r << 12) + (d << 6) + c];
      unsigned short h, l;
      split2(v, &h, &l);
      frags[dbase + j] = h;
      frags[12288 + dbase + j] = l;
    }
  } else if (idx < 1536 + 2 * 1536) {
    int i2 = idx - 1536;
    int set = i2 / 1536;
    int i3 = i2 % 1536;
    int lane = i3 & 63;
    int ks = (i3 >> 6) & 1;
    int tci = (i3 >> 7) % 12;
    int c = tci * 16 + (lane & 15);
    unsigned short* hi = frags + (size_t)(2 + 2 * set) * 12288;
    unsigned short* lo = hi + 12288;
    size_t dbase = ((size_t)(tci * 2 + ks) * 64 + lane) * 8;
    const float* wsrc = set ? w_hh : w_ih;
#pragma unroll
    for (int j = 0; j < 8; ++j) {
      int k = ks * 32 + ((lane >> 4) << 3) + j;
      float v = wsrc[(c << 6) + k];
      unsigned short h, l;
      split2(v, &h, &l);
      hi[dbase + j] = h;
      lo[dbase + j] = l;
    }
  }
}

// ---------------- consolidated CSR build (validated R17/R18) ----------------

// per-block LDS histogram over the 128 dst-bins; one global atomic per (block,bin)
__global__ __launch_bounds__(256) void histo_kernel(
    const int* __restrict__ dst, unsigned* __restrict__ bincnt, int E) {
  __shared__ unsigned h[128];
  int tid = threadIdx.x;
  if (tid < 128) h[tid] = 0u;
  __syncthreads();
  int base = blockIdx.x * 2048;
  int lim = base + 2048;
  if (lim > E) lim = E;
  for (int e = base + tid; e < lim; e += 256)
    atomicAdd(&h[((unsigned)dst[e]) >> 10], 1u);
  __syncthreads();
  if (tid < 128) {
    unsigned v = h[tid];
    if (v) atomicAdd(&bincnt[tid], v);
  }
}

// exclusive scan over <=128 bins -> binbase, bincur; sentinels; stats zeroing
__global__ __launch_bounds__(128) void scan128_kernel(
    const unsigned* __restrict__ bincnt, unsigned* __restrict__ binbase,
    unsigned* __restrict__ bincur, unsigned* __restrict__ offs,
    float* __restrict__ stats, int nbins, int N) {
  __shared__ unsigned sm[128];
  int tid = threadIdx.x;
  stats[tid] = 0.f;  // folded memset (BN stats, 128 entries)
  unsigned v = (tid < nbins) ? bincnt[tid] : 0u;
  sm[tid] = v;
  __syncthreads();
  for (int ofs = 1; ofs < 128; ofs <<= 1) {
    unsigned add = (tid >= ofs) ? sm[tid - ofs] : 0u;
    __syncthreads();
    sm[tid] += add;
    __syncthreads();
  }
  unsigned excl = sm[tid] - v;
  if (tid < nbins) {
    binbase[tid] = excl;
    bincur[tid] = excl;
  }
  if (tid == 127) {
    binbase[nbins] = sm[127];  // = E
    offs[N] = sm[127];
  }
}

// pass 1: block-aggregated scatter into dst-bins.
#define SCHUNK 2048
__global__ __launch_bounds__(256) void bin_scatter_kernel(
    const int* __restrict__ src, const int* __restrict__ dst,
    const int* __restrict__ rel, const float* __restrict__ norm,
    unsigned* __restrict__ bincur, uint2* __restrict__ binbuf, int E) {
  __shared__ unsigned cnt[128];
  __shared__ unsigned base[128];
  int tid = threadIdx.x;
  int start = blockIdx.x * SCHUNK;
  if (tid < 128) cnt[tid] = 0u;
  __syncthreads();
  unsigned mybin[8];
  uint2 myrec[8];
#pragma unroll
  for (int i = 0; i < 8; ++i) {
    int e = start + i * 256 + tid;
    if (e < E) {
      int d = dst[e];
      mybin[i] = (unsigned)d >> 10;
      myrec[i].x = (unsigned)src[e] | ((unsigned)rel[e] << 17) |
                   ((unsigned)(d & 1023) << 19);
      myrec[i].y = __builtin_bit_cast(unsigned, norm[e]);
      atomicAdd(&cnt[mybin[i]], 1u);
    } else {
      mybin[i] = 0xFFFFFFFFu;
    }
  }
  __syncthreads();
  if (tid < 128) {
    unsigned c = cnt[tid];
    base[tid] = c ? atomicAdd(&bincur[tid], c) : 0u;
    cnt[tid] = 0u;
  }
  __syncthreads();
#pragma unroll
  for (int i = 0; i < 8; ++i) {
    if (mybin[i] != 0xFFFFFFFFu) {
      unsigned r = atomicAdd(&cnt[mybin[i]], 1u);
      binbuf[base[mybin[i]] + r] = myrec[i];
    }
  }
}

// pass 2: per-bin (dst,rel) counting sort; computes offs[n] and rcnt[n] in-block
__global__ __launch_bounds__(1024) void bin_sort_kernel(
    const uint2* __restrict__ binbuf, const unsigned* __restrict__ binbase,
    uint2* __restrict__ epack, unsigned* __restrict__ offs,
    unsigned* __restrict__ rcnt, int N) {
  __shared__ unsigned cnt[3 * 1024];
  __shared__ unsigned pos[1024];
  int bin = blockIdx.x;
  int base = bin << 10;
  int tid = threadIdx.x;
  unsigned start = binbase[bin];
  unsigned end = binbase[bin + 1];
  cnt[tid] = 0u;
  cnt[1024 + tid] = 0u;
  cnt[2048 + tid] = 0u;
  __syncthreads();
  for (unsigned j = start + tid; j < end; j += 1024) {
    uint2 rec = binbuf[j];
    atomicAdd(&cnt[((rec.x >> 17) & 3) * 1024 + (rec.x >> 19)], 1u);
  }
  __syncthreads();
  unsigned c0 = cnt[tid], c1 = cnt[1024 + tid], c2 = cnt[2048 + tid];
  unsigned tot = c0 + c1 + c2;
  int n = base + tid;
  if (n < N) rcnt[n] = c0 | (c1 << 16);
  pos[tid] = tot;
  __syncthreads();
  for (int ofs = 1; ofs < 1024; ofs <<= 1) {
    unsigned add = (tid >= ofs) ? pos[tid - ofs] : 0u;
    __syncthreads();
    pos[tid] += add;
    __syncthreads();
  }
  unsigned o = start + pos[tid] - tot;
  if (n < N) offs[n] = o;
  cnt[tid] = o;
  cnt[1024 + tid] = o + c0;
  cnt[2048 + tid] = o + c0 + c1;
  __syncthreads();
  for (unsigned j = start + tid; j < end; j += 1024) {
    uint2 rec = binbuf[j];
    unsigned p = atomicAdd(&cnt[((rec.x >> 17) & 3) * 1024 + (rec.x >> 19)], 1u);
    epack[p] = rec;
  }
}

// ---------------- fused layer: gather + Wcat-GEMM + GRU ----------------
// Per block: 16 nodes. Phase 1 gathers z[3][64] (rel-sorted runs, fp32),
// 4-deep unrolled inside the PROVEN lambda shape. (Byte-identical to R22.)
// Phase 2: K=192 split-bf16 MFMA -> swh tile (LDS). Phase 3: GRU MFMAs +
// register gates; LAYER=0 writes fp32 h1, LAYER=1 reads hf rows for the
// h-path (split in-kernel) and hp (exact fp32), writes fp32 out.
// NOTE: BN-stats fusion into this kernel is empirically poison (4/4 broken
// variants, R13/14/15/18) — keep bn_stats as a separate kernel.

template <int LAYER>
__global__ __launch_bounds__(256) void layer_kernel(
    const float* __restrict__ xf, const unsigned* __restrict__ offs,
    const unsigned* __restrict__ rcnt, const uint2* __restrict__ epack,
    const unsigned short* __restrict__ wft,
    const unsigned short* __restrict__ wfi, const unsigned short* __restrict__ wfh,
    const float* __restrict__ b_ih, const float* __restrict__ b_hh,
    float* __restrict__ outf, int N) {
  __shared__ float zld[16][197];
  __shared__ float swht[16][69];
  int tid = threadIdx.x;
  int n0 = blockIdx.x << 4;

  // ---- phase 1: gather (one 16-lane group per node; rel runs) ----
  {
    int g = tid >> 4, l16 = tid & 15;
    int n = n0 + g;
    int c4 = l16 << 2;
    float z0[4] = {}, z1[4] = {}, z2[4] = {};
    if (n < N) {
      unsigned a = offs[n], b = offs[n + 1];
      unsigned rc = rcnt[n];
      unsigned b1 = a + (rc & 0xFFFFu), b2 = b1 + (rc >> 16);
      auto run = [&](unsigned s, unsigned e, float* z) {
        unsigned j = s;
        for (; j + 4 <= e; j += 4) {
          uint2 e0 = epack[j], e1 = epack[j + 1];
          uint2 e2 = epack[j + 2], e3 = epack[j + 3];
          float4 v0 = *(const float4*)(xf + (((size_t)(e0.x & 0x1FFFFu)) << 6) + c4);
          float4 v1 = *(const float4*)(xf + (((size_t)(e1.x & 0x1FFFFu)) << 6) + c4);
          float4 v2 = *(const float4*)(xf + (((size_t)(e2.x & 0x1FFFFu)) << 6) + c4);
          float4 v3 = *(const float4*)(xf + (((size_t)(e3.x & 0x1FFFFu)) << 6) + c4);
          float nv0 = __builtin_bit_cast(float, e0.y);
          float nv1 = __builtin_bit_cast(float, e1.y);
          float nv2 = __builtin_bit_cast(float, e2.y);
          float nv3 = __builtin_bit_cast(float, e3.y);
          z[0] = fmaf(nv0, v0.x, fmaf(nv1, v1.x, fmaf(nv2, v2.x, fmaf(nv3, v3.x, z[0]))));
          z[1] = fmaf(nv0, v0.y, fmaf(nv1, v1.y, fmaf(nv2, v2.y, fmaf(nv3, v3.y, z[1]))));
          z[2] = fmaf(nv0, v0.z, fmaf(nv1, v1.z, fmaf(nv2, v2.z, fmaf(nv3, v3.z, z[2]))));
          z[3] = fmaf(nv0, v0.w, fmaf(nv1, v1.w, fmaf(nv2, v2.w, fmaf(nv3, v3.w, z[3]))));
        }
        for (; j + 2 <= e; j += 2) {
          uint2 e0 = epack[j], e1 = epack[j + 1];
          float4 v0 = *(const float4*)(xf + (((size_t)(e0.x & 0x1FFFFu)) << 6) + c4);
          float4 v1 = *(const float4*)(xf + (((size_t)(e1.x & 0x1FFFFu)) << 6) + c4);
          float nv0 = __builtin_bit_cast(float, e0.y);
          float nv1 = __builtin_bit_cast(float, e1.y);
          z[0] = fmaf(nv0, v0.x, fmaf(nv1, v1.x, z[0]));
          z[1] = fmaf(nv0, v0.y, fmaf(nv1, v1.y, z[1]));
          z[2] = fmaf(nv0, v0.z, fmaf(nv1, v1.z, z[2]));
          z[3] = fmaf(nv0, v0.w, fmaf(nv1, v1.w, z[3]));
        }
        if (j < e) {
          uint2 e0 = epack[j];
          float4 v0 = *(const float4*)(xf + (((size_t)(e0.x & 0x1FFFFu)) << 6) + c4);
          float nv0 = __builtin_bit_cast(float, e0.y);
          z[0] = fmaf(nv0, v0.x, z[0]);
          z[1] = fmaf(nv0, v0.y, z[1]);
          z[2] = fmaf(nv0, v0.z, z[2]);
          z[3] = fmaf(nv0, v0.w, z[3]);
        }
      };
      run(a, b1, z0);
      run(b1, b2, z1);
      run(b2, b, z2);
    }
#pragma unroll
    for (int i = 0; i < 4; ++i) {
      zld[g][c4 + i] = z0[i];
      zld[g][64 + c4 + i] = z1[i];
      zld[g][128 + c4 + i] = z2[i];
    }
  }
  __syncthreads();

  // ---- phase 2: z @ Wcat (K=192) -> swht ----
  int lane = tid & 63, w = tid >> 6;
  int r15 = lane & 15, kq = lane >> 4;
  {
    const short8* fh = (const short8*)wft;
    const short8* fl = (const short8*)(wft + 12288);
    f32x4 acc = {0.f, 0.f, 0.f, 0.f};
#pragma unroll
    for (int ks = 0; ks < 6; ++ks) {
      const float* zr = &zld[r15][ks * 32 + (kq << 3)];
      short8 th, tl;
#pragma unroll
      for (int jj = 0; jj < 8; ++jj) {
        unsigned short h_, l_;
        split2(zr[jj], &h_, &l_);
        th[jj] = (short)h_;
        tl[jj] = (short)l_;
      }
      bf16x8 ahi = __builtin_bit_cast(bf16x8, th);
      bf16x8 alo = __builtin_bit_cast(bf16x8, tl);
      bf16x8 bhi = __builtin_bit_cast(bf16x8, fh[(w * 6 + ks) * 64 + lane]);
      bf16x8 blo = __builtin_bit_cast(bf16x8, fl[(w * 6 + ks) * 64 + lane]);
      acc = MFMA16(ahi, bhi, acc);
      acc = MFMA16(ahi, blo, acc);
      acc = MFMA16(alo, bhi, acc);
    }
    int c = (w << 4) + r15;
#pragma unroll
    for (int reg = 0; reg < 4; ++reg) swht[(kq << 2) + reg][c] = acc[reg];
  }
  __syncthreads();

  // ---- phase 3: GRU ----
  {
    int c = (w << 4) + r15;
    int row = n0 + r15;
    if (row >= N) row = N - 1;

    bf16x8 axh[2], axl[2], ahh2[2], ahl2[2];
#pragma unroll
    for (int ks = 0; ks < 2; ++ks) {
      const float* sr = &swht[r15][(ks << 5) + (kq << 3)];
      short8 th, tl;
#pragma unroll
      for (int jj = 0; jj < 8; ++jj) {
        unsigned short h_, l_;
        split2(sr[jj], &h_, &l_);
        th[jj] = (short)h_;
        tl[jj] = (short)l_;
      }
      axh[ks] = __builtin_bit_cast(bf16x8, th);
      axl[ks] = __builtin_bit_cast(bf16x8, tl);
    }
    if (LAYER) {
#pragma unroll
      for (int ks = 0; ks < 2; ++ks) {
        const float* hr = xf + (((size_t)row) << 6) + ks * 32 + (kq << 3);
        float4 h0 = *(const float4*)hr;
        float4 h1v = *(const float4*)(hr + 4);
        float hv[8] = {h0.x, h0.y, h0.z, h0.w, h1v.x, h1v.y, h1v.z, h1v.w};
        short8 th, tl;
#pragma unroll
        for (int jj = 0; jj < 8; ++jj) {
          unsigned short h_, l_;
          split2(hv[jj], &h_, &l_);
          th[jj] = (short)h_;
          tl[jj] = (short)l_;
        }
        ahh2[ks] = __builtin_bit_cast(bf16x8, th);
        ahl2[ks] = __builtin_bit_cast(bf16x8, tl);
      }
    }

    const short8* fih = (const short8*)wfi;
    const short8* fil = (const short8*)(wfi + 12288);
    const short8* fhh = (const short8*)wfh;
    const short8* fhl = (const short8*)(wfh + 12288);
    f32x4 accx[3], acch[3];
#pragma unroll
    for (int g = 0; g < 3; ++g) {
      accx[g] = (f32x4){0.f, 0.f, 0.f, 0.f};
      acch[g] = (f32x4){0.f, 0.f, 0.f, 0.f};
#pragma unroll
      for (int ks = 0; ks < 2; ++ks) {
        int tci = (g << 2) + w;
        bf16x8 bih = __builtin_bit_cast(bf16x8, fih[(tci * 2 + ks) * 64 + lane]);
        bf16x8 bil = __builtin_bit_cast(bf16x8, fil[(tci * 2 + ks) * 64 + lane]);
        accx[g] = MFMA16(axh[ks], bih, accx[g]);
        accx[g] = MFMA16(axh[ks], bil, accx[g]);
        accx[g] = MFMA16(axl[ks], bih, accx[g]);
        if (LAYER) {
          bf16x8 bhh = __builtin_bit_cast(bf16x8, fhh[(tci * 2 + ks) * 64 + lane]);
          bf16x8 bhl = __builtin_bit_cast(bf16x8, fhl[(tci * 2 + ks) * 64 + lane]);
          acch[g] = MFMA16(ahh2[ks], bhh, acch[g]);
          acch[g] = MFMA16(ahh2[ks], bhl, acch[g]);
          acch[g] = MFMA16(ahl2[ks], bhh, acch[g]);
        }
      }
    }

    float bi0 = b_ih[c], bi1 = b_ih[64 + c], bi2 = b_ih[128 + c];
    float bh0 = b_hh[c], bh1 = b_hh[64 + c], bh2 = b_hh[128 + c];
#pragma unroll
    for (int reg = 0; reg < 4; ++reg) {
      int n = n0 + (kq << 2) + reg;
      if (n >= N) break;
      size_t idx = (((size_t)n) << 6) + c;
      float hp = LAYER ? xf[idx] : 0.f;
      float gir = accx[0][reg] + bi0;
      float giz = accx[1][reg] + bi1;
      float gin = accx[2][reg] + bi2;
      float ghr = (LAYER ? acch[0][reg] : 0.f) + bh0;
      float ghz = (LAYER ? acch[1][reg] : 0.f) + bh1;
      float ghn = (LAYER ? acch[2][reg] : 0.f) + bh2;
      float r = fast_rcp(1.f + __expf(-(gir + ghr)));
      float z = fast_rcp(1.f + __expf(-(giz + ghz)));
      float nn = 1.f - 2.f * fast_rcp(1.f + __expf(2.f * (gin + r * ghn)));
      outf[idx] = (1.f - z) * nn + z * hp;
    }
  }
}

// ---------------- batchnorm ----------------

__global__ __launch_bounds__(256) void bn_stats_kernel(
    const float* __restrict__ h, float* __restrict__ stats, int N) {
  int tid = threadIdx.x;
  int c = tid & 63;
  float s = 0.f, ss = 0.f;
  for (int n = blockIdx.x * 4 + (tid >> 6); n < N; n += gridDim.x * 4) {
    float v = h[(size_t)n * 64 + c];
    s += v;
    ss += v * v;
  }
  __shared__ float sm[2][256];
  sm[0][tid] = s;
  sm[1][tid] = ss;
  __syncthreads();
  if (tid < 64) {
    s = sm[0][tid] + sm[0][tid + 64] + sm[0][tid + 128] + sm[0][tid + 192];
    ss = sm[1][tid] + sm[1][tid + 64] + sm[1][tid + 128] + sm[1][tid + 192];
    atomicAdd(&stats[tid], s);
    atomicAdd(&stats[64 + tid], ss);
  }
}

__global__ __launch_bounds__(256) void bn_apply_kernel(
    float* out, const float* __restrict__ stats,
    const float* __restrict__ gamma, const float* __restrict__ beta,
    int N, int total) {
  int idx = blockIdx.x * 256 + threadIdx.x;
  if (idx >= total) return;
  int c = idx & 63;
  float invN = 1.f / (float)N;
  float mean = stats[c] * invN;
  float var = stats[64 + c] * invN - mean * mean;
  float sc = rsqrtf(var + 1e-5f) * gamma[c];
  float sh = beta[c] - mean * sc;
  out[idx] = out[idx] * sc + sh;
}

// ---------------- launch ----------------

extern "C" void kernel_launch(void* const* d_in, const int* in_sizes, int n_in,
                              void* d_out, int out_size, void* d_ws, size_t ws_size,
                              hipStream_t stream) {
  const float* h     = (const float*)d_in[0];
  const float* norm  = (const float*)d_in[1];
  const float* W     = (const float*)d_in[2];
  const float* w_ih  = (const float*)d_in[3];
  const float* w_hh  = (const float*)d_in[4];
  const float* b_ih  = (const float*)d_in[5];
  const float* b_hh  = (const float*)d_in[6];
  const float* gamma = (const float*)d_in[7];
  const float* beta  = (const float*)d_in[8];
  const int* src     = (const int*)d_in[9];
  const int* dst     = (const int*)d_in[10];
  const int* rel     = (const int*)d_in[11];
  float* out = (float*)d_out;

  const int N = in_sizes[0] / 64;
  const int E = in_sizes[1];
  const int NT = (N + 15) / 16;
  const int NBINS = (N + 1023) / 1024;

  char* wsp = (char*)d_ws;
  float* hf = (float*)wsp;                      wsp += (size_t)N * 64 * 4;  // fp32 h1
  unsigned short* frags = (unsigned short*)wsp; wsp += 6 * 12288 * 2;
  unsigned* offs = (unsigned*)wsp;    wsp += ((size_t)N + 4) * 4;
  unsigned* rcnt = (unsigned*)wsp;    wsp += (size_t)N * 4;
  uint2* epack = (uint2*)wsp;         wsp += (size_t)E * 8;
  unsigned* bincnt = (unsigned*)wsp;  wsp += 128 * 4;
  float* stats = (float*)wsp;         wsp += 128 * 4;
  unsigned* binbase = (unsigned*)wsp; wsp += 132 * 4;
  unsigned* bincur = (unsigned*)wsp;  wsp += 128 * 4;

  uint2* binbuf = (uint2*)hf;  // aliases hf: dead until layer_kernel<0> writes it

  const unsigned short* frag_t = frags;
  const unsigned short* frag_i = frags + 2 * 12288;
  const unsigned short* frag_h = frags + 4 * 12288;

  // wprep also zeroes bincnt (folded memset)
  wprep_kernel<<<18, 256, 0, stream>>>(W, w_ih, w_hh, frags, bincnt);

  // consolidated CSR: histogram -> bin scan -> binned scatter -> (dst,rel) sort
  histo_kernel<<<(E + 2047) / 2048, 256, 0, stream>>>(dst, bincnt, E);
  scan128_kernel<<<1, 128, 0, stream>>>(bincnt, binbase, bincur, offs, stats,
                                        NBINS, N);
  bin_scatter_kernel<<<(E + SCHUNK - 1) / SCHUNK, 256, 0, stream>>>(
      src, dst, rel, norm, bincur, binbuf, E);
  bin_sort_kernel<<<NBINS, 1024, 0, stream>>>(binbuf, binbase, epack, offs,
                                              rcnt, N);

  // layer 0: gather from input h; GRU (hstate=0) -> fp32 h1
  layer_kernel<0><<<NT, 256, 0, stream>>>(h, offs, rcnt, epack, frag_t,
                                          frag_i, frag_h, b_ih, b_hh, hf, N);
  // layer 1: gather from h1; GRU (h-path from h1) -> fp32 out
  layer_kernel<1><<<NT, 256, 0, stream>>>(hf, offs, rcnt, epack, frag_t,
                                          frag_i, frag_h, b_ih, b_hh, out, N);

  bn_stats_kernel<<<256, 256, 0, stream>>>(out, stats, N);
  int total = N * 64;
  bn_apply_kernel<<<(total + 255) / 256, 256, 0, stream>>>(out, stats, gamma,
                                                           beta, N, total);
}

// Round 24
// 247.158 us; speedup vs baseline: 1.9154x; 1.0752x over previous
//
#include <hip/hip_runtime.h>

typedef __bf16 bf16x8 __attribute__((ext_vector_type(8)));
typedef float f32x4 __attribute__((ext_vector_type(4)));
typedef short short8 __attribute__((ext_vector_type(8)));

#define MFMA16(a, b, c) __builtin_amdgcn_mfma_f32_16x16x32_bf16(a, b, c, 0, 0, 0)

__device__ inline unsigned short bf16_rne(float x) {
  unsigned u = __builtin_bit_cast(unsigned, x);
  return (unsigned short)((u + 0x7FFFu + ((u >> 16) & 1u)) >> 16);
}
__device__ inline float bf16_tof(unsigned short s) {
  unsigned u = ((unsigned)s) << 16;
  return __builtin_bit_cast(float, u);
}
__device__ inline void split2(float x, unsigned short* hi, unsigned short* lo) {
  unsigned short h = bf16_rne(x);
  *hi = h;
  *lo = bf16_rne(x - bf16_tof(h));
}
__device__ inline float fast_rcp(float x) { return __builtin_amdgcn_rcpf(x); }

// ---------------- weight frag prep (+ bincnt zeroing) ----------------
// set0 (Wcat, K=192): ((tci*6+ks)*64+lane)*8+j, hi frags[0], lo frags[12288].
// set1 (w_ih) / set2 (w_hh): 12 col-tiles x 2 k-chunks at (2+2*set)*12288.

__global__ __launch_bounds__(256) void wprep_kernel(
    const float* __restrict__ W, const float* __restrict__ w_ih,
    const float* __restrict__ w_hh, unsigned short* __restrict__ frags,
    unsigned* __restrict__ bincnt) {
  int idx = blockIdx.x * 256 + threadIdx.x;
  if (idx < 128) bincnt[idx] = 0u;  // folded memset (histogram bins)
  if (idx < 1536) {
    int lane = idx & 63;
    int ks = (idx >> 6) % 6;
    int tci = idx / (6 * 64);
    int c = tci * 16 + (lane & 15);
    size_t dbase = ((size_t)(tci * 6 + ks) * 64 + lane) * 8;
#pragma unroll
    for (int j = 0; j < 8; ++j) {
      int k = ks * 32 + ((lane >> 4) << 3) + j;  // 0..191
      int r = k >> 6, d = k & 63;
      float v = W[(r << 12) + (d << 6) + c];
      unsigned short h, l;
      split2(v, &h, &l);
      frags[dbase + j] = h;
      frags[12288 + dbase + j] = l;
    }
  } else if (idx < 1536 + 2 * 1536) {
    int i2 = idx - 1536;
    int set = i2 / 1536;
    int i3 = i2 % 1536;
    int lane = i3 & 63;
    int ks = (i3 >> 6) & 1;
    int tci = (i3 >> 7) % 12;
    int c = tci * 16 + (lane & 15);
    unsigned short* hi = frags + (size_t)(2 + 2 * set) * 12288;
    unsigned short* lo = hi + 12288;
    size_t dbase = ((size_t)(tci * 2 + ks) * 64 + lane) * 8;
    const float* wsrc = set ? w_hh : w_ih;
#pragma unroll
    for (int j = 0; j < 8; ++j) {
      int k = ks * 32 + ((lane >> 4) << 3) + j;
      float v = wsrc[(c << 6) + k];
      unsigned short h, l;
      split2(v, &h, &l);
      hi[dbase + j] = h;
      lo[dbase + j] = l;
    }
  }
}

// ---------------- consolidated CSR build (validated R17/R23) ----------------

// per-block LDS histogram over the 128 dst-bins; one global atomic per (block,bin)
__global__ __launch_bounds__(256) void histo_kernel(
    const int* __restrict__ dst, unsigned* __restrict__ bincnt, int E) {
  __shared__ unsigned h[128];
  int tid = threadIdx.x;
  if (tid < 128) h[tid] = 0u;
  __syncthreads();
  int base = blockIdx.x * 2048;
  int lim = base + 2048;
  if (lim > E) lim = E;
  for (int e = base + tid; e < lim; e += 256)
    atomicAdd(&h[((unsigned)dst[e]) >> 10], 1u);
  __syncthreads();
  if (tid < 128) {
    unsigned v = h[tid];
    if (v) atomicAdd(&bincnt[tid], v);
  }
}

// exclusive scan over <=128 bins -> binbase, bincur; sentinels; stats zeroing
__global__ __launch_bounds__(128) void scan128_kernel(
    const unsigned* __restrict__ bincnt, unsigned* __restrict__ binbase,
    unsigned* __restrict__ bincur, unsigned* __restrict__ offs,
    float* __restrict__ stats, int nbins, int N) {
  __shared__ unsigned sm[128];
  int tid = threadIdx.x;
  stats[tid] = 0.f;  // folded memset (BN stats, 128 entries)
  unsigned v = (tid < nbins) ? bincnt[tid] : 0u;
  sm[tid] = v;
  __syncthreads();
  for (int ofs = 1; ofs < 128; ofs <<= 1) {
    unsigned add = (tid >= ofs) ? sm[tid - ofs] : 0u;
    __syncthreads();
    sm[tid] += add;
    __syncthreads();
  }
  unsigned excl = sm[tid] - v;
  if (tid < nbins) {
    binbase[tid] = excl;
    bincur[tid] = excl;
  }
  if (tid == 127) {
    binbase[nbins] = sm[127];  // = E
    offs[N] = sm[127];
  }
}

// pass 1: block-aggregated scatter into dst-bins.
#define SCHUNK 2048
__global__ __launch_bounds__(256) void bin_scatter_kernel(
    const int* __restrict__ src, const int* __restrict__ dst,
    const int* __restrict__ rel, const float* __restrict__ norm,
    unsigned* __restrict__ bincur, uint2* __restrict__ binbuf, int E) {
  __shared__ unsigned cnt[128];
  __shared__ unsigned base[128];
  int tid = threadIdx.x;
  int start = blockIdx.x * SCHUNK;
  if (tid < 128) cnt[tid] = 0u;
  __syncthreads();
  unsigned mybin[8];
  uint2 myrec[8];
#pragma unroll
  for (int i = 0; i < 8; ++i) {
    int e = start + i * 256 + tid;
    if (e < E) {
      int d = dst[e];
      mybin[i] = (unsigned)d >> 10;
      myrec[i].x = (unsigned)src[e] | ((unsigned)rel[e] << 17) |
                   ((unsigned)(d & 1023) << 19);
      myrec[i].y = __builtin_bit_cast(unsigned, norm[e]);
      atomicAdd(&cnt[mybin[i]], 1u);
    } else {
      mybin[i] = 0xFFFFFFFFu;
    }
  }
  __syncthreads();
  if (tid < 128) {
    unsigned c = cnt[tid];
    base[tid] = c ? atomicAdd(&bincur[tid], c) : 0u;
    cnt[tid] = 0u;
  }
  __syncthreads();
#pragma unroll
  for (int i = 0; i < 8; ++i) {
    if (mybin[i] != 0xFFFFFFFFu) {
      unsigned r = atomicAdd(&cnt[mybin[i]], 1u);
      binbuf[base[mybin[i]] + r] = myrec[i];
    }
  }
}

// pass 2: per-bin (dst,rel) counting sort; computes offs[n] and rcnt[n] in-block
__global__ __launch_bounds__(1024) void bin_sort_kernel(
    const uint2* __restrict__ binbuf, const unsigned* __restrict__ binbase,
    uint2* __restrict__ epack, unsigned* __restrict__ offs,
    unsigned* __restrict__ rcnt, int N) {
  __shared__ unsigned cnt[3 * 1024];
  __shared__ unsigned pos[1024];
  int bin = blockIdx.x;
  int base = bin << 10;
  int tid = threadIdx.x;
  unsigned start = binbase[bin];
  unsigned end = binbase[bin + 1];
  cnt[tid] = 0u;
  cnt[1024 + tid] = 0u;
  cnt[2048 + tid] = 0u;
  __syncthreads();
  for (unsigned j = start + tid; j < end; j += 1024) {
    uint2 rec = binbuf[j];
    atomicAdd(&cnt[((rec.x >> 17) & 3) * 1024 + (rec.x >> 19)], 1u);
  }
  __syncthreads();
  unsigned c0 = cnt[tid], c1 = cnt[1024 + tid], c2 = cnt[2048 + tid];
  unsigned tot = c0 + c1 + c2;
  int n = base + tid;
  if (n < N) rcnt[n] = c0 | (c1 << 16);
  pos[tid] = tot;
  __syncthreads();
  for (int ofs = 1; ofs < 1024; ofs <<= 1) {
    unsigned add = (tid >= ofs) ? pos[tid - ofs] : 0u;
    __syncthreads();
    pos[tid] += add;
    __syncthreads();
  }
  unsigned o = start + pos[tid] - tot;
  if (n < N) offs[n] = o;
  cnt[tid] = o;
  cnt[1024 + tid] = o + c0;
  cnt[2048 + tid] = o + c0 + c1;
  __syncthreads();
  for (unsigned j = start + tid; j < end; j += 1024) {
    uint2 rec = binbuf[j];
    unsigned p = atomicAdd(&cnt[((rec.x >> 17) & 3) * 1024 + (rec.x >> 19)], 1u);
    epack[p] = rec;
  }
}

// ---------------- fused layer: gather + Wcat-GEMM + GRU ----------------
// Per block: 16 nodes. Phase 1 gathers z[3][64] (rel-sorted runs, fp32),
// 4-deep unrolled inside the PROVEN lambda shape. (Byte-identical to R23.)
// Phase 2: K=192 split-bf16 MFMA -> swh tile (LDS). Phase 3: GRU MFMAs +
// register gates; LAYER=0 writes fp32 h1, LAYER=1 reads hf rows for the
// h-path (split in-kernel) and hp (exact fp32), writes fp32 out.
// NOTE: BN-stats fusion into this kernel is empirically poison (4/4 broken
// variants, R13/14/15/18) — keep bn_stats as a separate kernel.

template <int LAYER>
__global__ __launch_bounds__(256) void layer_kernel(
    const float* __restrict__ xf, const unsigned* __restrict__ offs,
    const unsigned* __restrict__ rcnt, const uint2* __restrict__ epack,
    const unsigned short* __restrict__ wft,
    const unsigned short* __restrict__ wfi, const unsigned short* __restrict__ wfh,
    const float* __restrict__ b_ih, const float* __restrict__ b_hh,
    float* __restrict__ outf, int N) {
  __shared__ float zld[16][197];
  __shared__ float swht[16][69];
  int tid = threadIdx.x;
  int n0 = blockIdx.x << 4;

  // ---- phase 1: gather (one 16-lane group per node; rel runs) ----
  {
    int g = tid >> 4, l16 = tid & 15;
    int n = n0 + g;
    int c4 = l16 << 2;
    float z0[4] = {}, z1[4] = {}, z2[4] = {};
    if (n < N) {
      unsigned a = offs[n], b = offs[n + 1];
      unsigned rc = rcnt[n];
      unsigned b1 = a + (rc & 0xFFFFu), b2 = b1 + (rc >> 16);
      auto run = [&](unsigned s, unsigned e, float* z) {
        unsigned j = s;
        for (; j + 4 <= e; j += 4) {
          uint2 e0 = epack[j], e1 = epack[j + 1];
          uint2 e2 = epack[j + 2], e3 = epack[j + 3];
          float4 v0 = *(const float4*)(xf + (((size_t)(e0.x & 0x1FFFFu)) << 6) + c4);
          float4 v1 = *(const float4*)(xf + (((size_t)(e1.x & 0x1FFFFu)) << 6) + c4);
          float4 v2 = *(const float4*)(xf + (((size_t)(e2.x & 0x1FFFFu)) << 6) + c4);
          float4 v3 = *(const float4*)(xf + (((size_t)(e3.x & 0x1FFFFu)) << 6) + c4);
          float nv0 = __builtin_bit_cast(float, e0.y);
          float nv1 = __builtin_bit_cast(float, e1.y);
          float nv2 = __builtin_bit_cast(float, e2.y);
          float nv3 = __builtin_bit_cast(float, e3.y);
          z[0] = fmaf(nv0, v0.x, fmaf(nv1, v1.x, fmaf(nv2, v2.x, fmaf(nv3, v3.x, z[0]))));
          z[1] = fmaf(nv0, v0.y, fmaf(nv1, v1.y, fmaf(nv2, v2.y, fmaf(nv3, v3.y, z[1]))));
          z[2] = fmaf(nv0, v0.z, fmaf(nv1, v1.z, fmaf(nv2, v2.z, fmaf(nv3, v3.z, z[2]))));
          z[3] = fmaf(nv0, v0.w, fmaf(nv1, v1.w, fmaf(nv2, v2.w, fmaf(nv3, v3.w, z[3]))));
        }
        for (; j + 2 <= e; j += 2) {
          uint2 e0 = epack[j], e1 = epack[j + 1];
          float4 v0 = *(const float4*)(xf + (((size_t)(e0.x & 0x1FFFFu)) << 6) + c4);
          float4 v1 = *(const float4*)(xf + (((size_t)(e1.x & 0x1FFFFu)) << 6) + c4);
          float nv0 = __builtin_bit_cast(float, e0.y);
          float nv1 = __builtin_bit_cast(float, e1.y);
          z[0] = fmaf(nv0, v0.x, fmaf(nv1, v1.x, z[0]));
          z[1] = fmaf(nv0, v0.y, fmaf(nv1, v1.y, z[1]));
          z[2] = fmaf(nv0, v0.z, fmaf(nv1, v1.z, z[2]));
          z[3] = fmaf(nv0, v0.w, fmaf(nv1, v1.w, z[3]));
        }
        if (j < e) {
          uint2 e0 = epack[j];
          float4 v0 = *(const float4*)(xf + (((size_t)(e0.x & 0x1FFFFu)) << 6) + c4);
          float nv0 = __builtin_bit_cast(float, e0.y);
          z[0] = fmaf(nv0, v0.x, z[0]);
          z[1] = fmaf(nv0, v0.y, z[1]);
          z[2] = fmaf(nv0, v0.z, z[2]);
          z[3] = fmaf(nv0, v0.w, z[3]);
        }
      };
      run(a, b1, z0);
      run(b1, b2, z1);
      run(b2, b, z2);
    }
#pragma unroll
    for (int i = 0; i < 4; ++i) {
      zld[g][c4 + i] = z0[i];
      zld[g][64 + c4 + i] = z1[i];
      zld[g][128 + c4 + i] = z2[i];
    }
  }
  __syncthreads();

  // ---- phase 2: z @ Wcat (K=192) -> swht ----
  int lane = tid & 63, w = tid >> 6;
  int r15 = lane & 15, kq = lane >> 4;
  {
    const short8* fh = (const short8*)wft;
    const short8* fl = (const short8*)(wft + 12288);
    f32x4 acc = {0.f, 0.f, 0.f, 0.f};
#pragma unroll
    for (int ks = 0; ks < 6; ++ks) {
      const float* zr = &zld[r15][ks * 32 + (kq << 3)];
      short8 th, tl;
#pragma unroll
      for (int jj = 0; jj < 8; ++jj) {
        unsigned short h_, l_;
        split2(zr[jj], &h_, &l_);
        th[jj] = (short)h_;
        tl[jj] = (short)l_;
      }
      bf16x8 ahi = __builtin_bit_cast(bf16x8, th);
      bf16x8 alo = __builtin_bit_cast(bf16x8, tl);
      bf16x8 bhi = __builtin_bit_cast(bf16x8, fh[(w * 6 + ks) * 64 + lane]);
      bf16x8 blo = __builtin_bit_cast(bf16x8, fl[(w * 6 + ks) * 64 + lane]);
      acc = MFMA16(ahi, bhi, acc);
      acc = MFMA16(ahi, blo, acc);
      acc = MFMA16(alo, bhi, acc);
    }
    int c = (w << 4) + r15;
#pragma unroll
    for (int reg = 0; reg < 4; ++reg) swht[(kq << 2) + reg][c] = acc[reg];
  }
  __syncthreads();

  // ---- phase 3: GRU ----
  {
    int c = (w << 4) + r15;
    int row = n0 + r15;
    if (row >= N) row = N - 1;

    bf16x8 axh[2], axl[2], ahh2[2], ahl2[2];
#pragma unroll
    for (int ks = 0; ks < 2; ++ks) {
      const float* sr = &swht[r15][(ks << 5) + (kq << 3)];
      short8 th, tl;
#pragma unroll
      for (int jj = 0; jj < 8; ++jj) {
        unsigned short h_, l_;
        split2(sr[jj], &h_, &l_);
        th[jj] = (short)h_;
        tl[jj] = (short)l_;
      }
      axh[ks] = __builtin_bit_cast(bf16x8, th);
      axl[ks] = __builtin_bit_cast(bf16x8, tl);
    }
    if (LAYER) {
#pragma unroll
      for (int ks = 0; ks < 2; ++ks) {
        const float* hr = xf + (((size_t)row) << 6) + ks * 32 + (kq << 3);
        float4 h0 = *(const float4*)hr;
        float4 h1v = *(const float4*)(hr + 4);
        float hv[8] = {h0.x, h0.y, h0.z, h0.w, h1v.x, h1v.y, h1v.z, h1v.w};
        short8 th, tl;
#pragma unroll
        for (int jj = 0; jj < 8; ++jj) {
          unsigned short h_, l_;
          split2(hv[jj], &h_, &l_);
          th[jj] = (short)h_;
          tl[jj] = (short)l_;
        }
        ahh2[ks] = __builtin_bit_cast(bf16x8, th);
        ahl2[ks] = __builtin_bit_cast(bf16x8, tl);
      }
    }

    const short8* fih = (const short8*)wfi;
    const short8* fil = (const short8*)(wfi + 12288);
    const short8* fhh = (const short8*)wfh;
    const short8* fhl = (const short8*)(wfh + 12288);
    f32x4 accx[3], acch[3];
#pragma unroll
    for (int g = 0; g < 3; ++g) {
      accx[g] = (f32x4){0.f, 0.f, 0.f, 0.f};
      acch[g] = (f32x4){0.f, 0.f, 0.f, 0.f};
#pragma unroll
      for (int ks = 0; ks < 2; ++ks) {
        int tci = (g << 2) + w;
        bf16x8 bih = __builtin_bit_cast(bf16x8, fih[(tci * 2 + ks) * 64 + lane]);
        bf16x8 bil = __builtin_bit_cast(bf16x8, fil[(tci * 2 + ks) * 64 + lane]);
        accx[g] = MFMA16(axh[ks], bih, accx[g]);
        accx[g] = MFMA16(axh[ks], bil, accx[g]);
        accx[g] = MFMA16(axl[ks], bih, accx[g]);
        if (LAYER) {
          bf16x8 bhh = __builtin_bit_cast(bf16x8, fhh[(tci * 2 + ks) * 64 + lane]);
          bf16x8 bhl = __builtin_bit_cast(bf16x8, fhl[(tci * 2 + ks) * 64 + lane]);
          acch[g] = MFMA16(ahh2[ks], bhh, acch[g]);
          acch[g] = MFMA16(ahh2[ks], bhl, acch[g]);
          acch[g] = MFMA16(ahl2[ks], bhh, acch[g]);
        }
      }
    }

    float bi0 = b_ih[c], bi1 = b_ih[64 + c], bi2 = b_ih[128 + c];
    float bh0 = b_hh[c], bh1 = b_hh[64 + c], bh2 = b_hh[128 + c];
#pragma unroll
    for (int reg = 0; reg < 4; ++reg) {
      int n = n0 + (kq << 2) + reg;
      if (n >= N) break;
      size_t idx = (((size_t)n) << 6) + c;
      float hp = LAYER ? xf[idx] : 0.f;
      float gir = accx[0][reg] + bi0;
      float giz = accx[1][reg] + bi1;
      float gin = accx[2][reg] + bi2;
      float ghr = (LAYER ? acch[0][reg] : 0.f) + bh0;
      float ghz = (LAYER ? acch[1][reg] : 0.f) + bh1;
      float ghn = (LAYER ? acch[2][reg] : 0.f) + bh2;
      float r = fast_rcp(1.f + __expf(-(gir + ghr)));
      float z = fast_rcp(1.f + __expf(-(giz + ghz)));
      float nn = 1.f - 2.f * fast_rcp(1.f + __expf(2.f * (gin + r * ghn)));
      outf[idx] = (1.f - z) * nn + z * hp;
    }
  }
}

// ---------------- batchnorm (float4-vectorized) ----------------

__global__ __launch_bounds__(256) void bn_stats_kernel(
    const float* __restrict__ h, float* __restrict__ stats, int N) {
  int tid = threadIdx.x;
  int q = tid & 15;        // column quad: cols q*4 .. q*4+3
  int rg = tid >> 4;       // row group 0..15
  float s[4] = {}, ss[4] = {};
  for (int n = blockIdx.x * 16 + rg; n < N; n += gridDim.x * 16) {
    float4 v = *(const float4*)(h + (((size_t)n) << 6) + (q << 2));
    s[0] += v.x; ss[0] += v.x * v.x;
    s[1] += v.y; ss[1] += v.y * v.y;
    s[2] += v.z; ss[2] += v.z * v.z;
    s[3] += v.w; ss[3] += v.w * v.w;
  }
  __shared__ float sm_s[256][4];
  __shared__ float sm_ss[256][4];
#pragma unroll
  for (int k = 0; k < 4; ++k) {
    sm_s[tid][k] = s[k];
    sm_ss[tid][k] = ss[k];
  }
  __syncthreads();
  if (tid < 64) {
    int qq = tid >> 2, kk = tid & 3;  // column c = qq*4+kk
    float ts = 0.f, tss = 0.f;
#pragma unroll
    for (int g = 0; g < 16; ++g) {
      ts += sm_s[g * 16 + qq][kk];
      tss += sm_ss[g * 16 + qq][kk];
    }
    atomicAdd(&stats[tid], ts);
    atomicAdd(&stats[64 + tid], tss);
  }
}

__global__ __launch_bounds__(256) void bn_apply_kernel(
    float* out, const float* __restrict__ stats,
    const float* __restrict__ gamma, const float* __restrict__ beta,
    int N, int total4) {
  int i4 = blockIdx.x * 256 + threadIdx.x;
  if (i4 >= total4) return;
  int c4 = (i4 & 15) << 2;
  float invN = 1.f / (float)N;
  float4 v = *(float4*)(out + ((size_t)i4 << 2));
  float ov[4] = {v.x, v.y, v.z, v.w};
#pragma unroll
  for (int k = 0; k < 4; ++k) {
    int c = c4 + k;
    float mean = stats[c] * invN;
    float var = stats[64 + c] * invN - mean * mean;
    float sc = rsqrtf(var + 1e-5f) * gamma[c];
    float sh = beta[c] - mean * sc;
    ov[k] = ov[k] * sc + sh;
  }
  *(float4*)(out + ((size_t)i4 << 2)) = make_float4(ov[0], ov[1], ov[2], ov[3]);
}

// ---------------- launch ----------------

extern "C" void kernel_launch(void* const* d_in, const int* in_sizes, int n_in,
                              void* d_out, int out_size, void* d_ws, size_t ws_size,
                              hipStream_t stream) {
  const float* h     = (const float*)d_in[0];
  const float* norm  = (const float*)d_in[1];
  const float* W     = (const float*)d_in[2];
  const float* w_ih  = (const float*)d_in[3];
  const float* w_hh  = (const float*)d_in[4];
  const float* b_ih  = (const float*)d_in[5];
  const float* b_hh  = (const float*)d_in[6];
  const float* gamma = (const float*)d_in[7];
  const float* beta  = (const float*)d_in[8];
  const int* src     = (const int*)d_in[9];
  const int* dst     = (const int*)d_in[10];
  const int* rel     = (const int*)d_in[11];
  float* out = (float*)d_out;

  const int N = in_sizes[0] / 64;
  const int E = in_sizes[1];
  const int NT = (N + 15) / 16;
  const int NBINS = (N + 1023) / 1024;

  char* wsp = (char*)d_ws;
  float* hf = (float*)wsp;                      wsp += (size_t)N * 64 * 4;  // fp32 h1
  unsigned short* frags = (unsigned short*)wsp; wsp += 6 * 12288 * 2;
  unsigned* offs = (unsigned*)wsp;    wsp += ((size_t)N + 4) * 4;
  unsigned* rcnt = (unsigned*)wsp;    wsp += (size_t)N * 4;
  uint2* epack = (uint2*)wsp;         wsp += (size_t)E * 8;
  unsigned* bincnt = (unsigned*)wsp;  wsp += 128 * 4;
  float* stats = (float*)wsp;         wsp += 128 * 4;
  unsigned* binbase = (unsigned*)wsp; wsp += 132 * 4;
  unsigned* bincur = (unsigned*)wsp;  wsp += 128 * 4;

  uint2* binbuf = (uint2*)hf;  // aliases hf: dead until layer_kernel<0> writes it

  const unsigned short* frag_t = frags;
  const unsigned short* frag_i = frags + 2 * 12288;
  const unsigned short* frag_h = frags + 4 * 12288;

  // wprep also zeroes bincnt (folded memset)
  wprep_kernel<<<18, 256, 0, stream>>>(W, w_ih, w_hh, frags, bincnt);

  // consolidated CSR: histogram -> bin scan -> binned scatter -> (dst,rel) sort
  histo_kernel<<<(E + 2047) / 2048, 256, 0, stream>>>(dst, bincnt, E);
  scan128_kernel<<<1, 128, 0, stream>>>(bincnt, binbase, bincur, offs, stats,
                                        NBINS, N);
  bin_scatter_kernel<<<(E + SCHUNK - 1) / SCHUNK, 256, 0, stream>>>(
      src, dst, rel, norm, bincur, binbuf, E);
  bin_sort_kernel<<<NBINS, 1024, 0, stream>>>(binbuf, binbase, epack, offs,
                                              rcnt, N);

  // layer 0: gather from input h; GRU (hstate=0) -> fp32 h1
  layer_kernel<0><<<NT, 256, 0, stream>>>(h, offs, rcnt, epack, frag_t,
                                          frag_i, frag_h, b_ih, b_hh, hf, N);
  // layer 1: gather from h1; GRU (h-path from h1) -> fp32 out
  layer_kernel<1><<<NT, 256, 0, stream>>>(hf, offs, rcnt, epack, frag_t,
                                          frag_i, frag_h, b_ih, b_hh, out, N);

  bn_stats_kernel<<<256, 256, 0, stream>>>(out, stats, N);
  int total4 = N * 16;
  bn_apply_kernel<<<(total4 + 255) / 256, 256, 0, stream>>>(out, stats, gamma,
                                                            beta, N, total4);
}